// Round 1
// baseline (505.011 us; speedup 1.0000x reference)
//
#include <hip/hip_runtime.h>

#define BN_S 0.9999950000374997f

constexpr int BATCH = 64;

__device__ __forceinline__ float bnrelu(float x, float gs, float bb) {
    return fmaxf(fmaf(x, gs, bb), 0.f);
}

// 3x3 conv, pad 1. Each thread: one output pixel, 16 consecutive output channels.
// blockIdx.y selects the 16-channel group. Optional fused BN+ReLU on the input.
template<int CIN, int COUT, int HIN, int WIN, int HOUT, int WOUT, int STRIDE, bool PRE_BN>
__global__ __launch_bounds__(256) void conv3_k(
    const float* __restrict__ in, const float* __restrict__ w,
    const float* __restrict__ g, const float* __restrict__ bb,
    float* __restrict__ out)
{
    const int npix = BATCH * HOUT * WOUT;
    int pix = blockIdx.x * blockDim.x + threadIdx.x;
    if (pix >= npix) return;
    const int cog = blockIdx.y * 16;
    int wo = pix % WOUT; int t = pix / WOUT; int ho = t % HOUT; int b = t / HOUT;

    float acc[16];
#pragma unroll
    for (int i = 0; i < 16; ++i) acc[i] = 0.f;

    const int hbase = ho * STRIDE - 1;
    const int wbase = wo * STRIDE - 1;

    for (int ci = 0; ci < CIN; ++ci) {
        float gs = 0.f, bi = 0.f;
        if constexpr (PRE_BN) { gs = g[ci] * BN_S; bi = bb[ci]; }
        const float* inp = in + ((size_t)(b * CIN + ci)) * (HIN * WIN);
        const float* wp = w + ((size_t)(cog * CIN + ci)) * 9;
#pragma unroll
        for (int dh = 0; dh < 3; ++dh) {
            int hi = hbase + dh;
            if (hi < 0 || hi >= HIN) continue;
#pragma unroll
            for (int dw = 0; dw < 3; ++dw) {
                int wi = wbase + dw;
                if (wi < 0 || wi >= WIN) continue;
                float v = inp[hi * WIN + wi];
                if constexpr (PRE_BN) v = bnrelu(v, gs, bi);
#pragma unroll
                for (int co = 0; co < 16; ++co)
                    acc[co] = fmaf(v, wp[co * CIN * 9 + dh * 3 + dw], acc[co]);
            }
        }
    }
    float* op = out + (((size_t)(b * COUT + cog)) * HOUT + ho) * WOUT + wo;
#pragma unroll
    for (int co = 0; co < 16; ++co)
        op[(size_t)co * HOUT * WOUT] = acc[co];
}

// Second conv of a residual block: conv3x3(bnrelu2(y)) + shortcut.
// SC==1: shortcut = bnrelu1(xin) at same pixel (identity path, CSC==COUT).
// SC==2: shortcut = 1x1-conv(stride SSTR) over bnrelu1(xin), weights ws[COUT][CSC].
template<int CIN, int CSC, int COUT, int HOUT, int WOUT, int SC, int SSTR>
__global__ __launch_bounds__(256) void conv3s_k(
    const float* __restrict__ y, const float* __restrict__ w2,
    const float* __restrict__ g2, const float* __restrict__ b2,
    const float* __restrict__ xin, const float* __restrict__ g1,
    const float* __restrict__ b1, const float* __restrict__ ws,
    float* __restrict__ out)
{
    const int npix = BATCH * HOUT * WOUT;
    const int HX = HOUT * SSTR, WX = WOUT * SSTR;
    int pix = blockIdx.x * blockDim.x + threadIdx.x;
    if (pix >= npix) return;
    const int cog = blockIdx.y * 16;
    int wo = pix % WOUT; int t = pix / WOUT; int ho = t % HOUT; int b = t / HOUT;

    float acc[16];
#pragma unroll
    for (int i = 0; i < 16; ++i) acc[i] = 0.f;

    // main conv: stride 1, input dims = output dims
    for (int ci = 0; ci < CIN; ++ci) {
        float gs = g2[ci] * BN_S, bi = b2[ci];
        const float* inp = y + ((size_t)(b * CIN + ci)) * (HOUT * WOUT);
        const float* wp = w2 + ((size_t)(cog * CIN + ci)) * 9;
#pragma unroll
        for (int dh = 0; dh < 3; ++dh) {
            int hi = ho - 1 + dh;
            if (hi < 0 || hi >= HOUT) continue;
#pragma unroll
            for (int dw = 0; dw < 3; ++dw) {
                int wi = wo - 1 + dw;
                if (wi < 0 || wi >= WOUT) continue;
                float v = bnrelu(inp[hi * WOUT + wi], gs, bi);
#pragma unroll
                for (int co = 0; co < 16; ++co)
                    acc[co] = fmaf(v, wp[co * CIN * 9 + dh * 3 + dw], acc[co]);
            }
        }
    }

    // shortcut
    if constexpr (SC == 1) {
#pragma unroll
        for (int co = 0; co < 16; ++co) {
            int c = cog + co;
            float v = xin[(((size_t)(b * CSC + c)) * HX + ho) * WX + wo];
            acc[co] += bnrelu(v, g1[c] * BN_S, b1[c]);
        }
    } else {
        for (int ci = 0; ci < CSC; ++ci) {
            float v = bnrelu(xin[(((size_t)(b * CSC + ci)) * HX + ho * SSTR) * WX + wo * SSTR],
                             g1[ci] * BN_S, b1[ci]);
#pragma unroll
            for (int co = 0; co < 16; ++co)
                acc[co] = fmaf(v, ws[(size_t)(cog + co) * CSC + ci], acc[co]);
        }
    }

    float* op = out + (((size_t)(b * COUT + cog)) * HOUT + ho) * WOUT + wo;
#pragma unroll
    for (int co = 0; co < 16; ++co)
        op[(size_t)co * HOUT * WOUT] = acc[co];
}

// Prep: transpose ct_w (64,2080) -> wT (2080,64); build (row,col) pair table.
__global__ void f0_k(const float* __restrict__ ctw, float* __restrict__ wT,
                     unsigned short* __restrict__ rc)
{
    int idx = blockIdx.x * 256 + threadIdx.x;
    if (idx < 2080) {
        int r = (int)floorf((129.0f - sqrtf(16641.0f - 8.0f * (float)idx)) * 0.5f);
        if (r < 0) r = 0; if (r > 63) r = 63;
        while (r > 0 && (64 * r - r * (r - 1) / 2) > idx) --r;
        while (r < 63 && (64 * (r + 1) - (r + 1) * r / 2) <= idx) ++r;
        int c = r + (idx - (64 * r - r * (r - 1) / 2));
        rc[idx] = (unsigned short)((r << 8) | c);
    }
    if (idx < 2080 * 64) {
        int k = idx >> 6, o = idx & 63;
        wT[idx] = ctw[o * 2080 + k];
    }
}

// xp[b,p,c] = bnrelu(h3[b,c,p]) channels-last transpose
__global__ void f1_k(const float* __restrict__ h3, const float* __restrict__ g,
                     const float* __restrict__ bb, float* __restrict__ xp)
{
    int idx = blockIdx.x * 256 + threadIdx.x;
    if (idx >= BATCH * 135 * 64) return;
    int c = idx & 63; int p = (idx >> 6) % 135; int b = idx / (135 * 64);
    float v = h3[((size_t)(b * 64 + c)) * 135 + p];
    xp[idx] = bnrelu(v, g[c] * BN_S, bb[c]);
}

// A[p,o] = sum_k xp[p,r_k]*xp[p,c_k] * wT[k,o] + ct_b[o]
// block: 256 threads, 64 pixels x 64 outs, 4x4 micro-tiles, K chunked by 32.
__global__ __launch_bounds__(256) void f2_k(
    const float* __restrict__ xp, const float* __restrict__ wT,
    const unsigned short* __restrict__ rc, const float* __restrict__ ctb,
    float* __restrict__ A)
{
    __shared__ float xs[64][65];
    __shared__ float Zt[32][64];
    __shared__ float Wt[32][64];
    int t = threadIdx.x;
    int p0 = blockIdx.x * 64;

    // stage xp tile (4096 floats, 16 per thread)
    {
        const float4* src = (const float4*)(xp + (size_t)p0 * 64);
#pragma unroll
        for (int j = 0; j < 4; ++j) {
            int f = t * 16 + j * 4;
            float4 v = src[f >> 2];
            int p = f >> 6, c = f & 63;
            xs[p][c] = v.x; xs[p][c + 1] = v.y; xs[p][c + 2] = v.z; xs[p][c + 3] = v.w;
        }
    }

    float accum[4][4] = {};
    const int pb = (t >> 4) * 4, ob = (t & 15) * 4;
    const int zrow = (t * 8) >> 6, pz = (t * 8) & 63;

    for (int k0 = 0; k0 < 2080; k0 += 32) {
        __syncthreads();
        // stage W tile: 8 consecutive floats per thread
        {
            int f = t * 8;
            int kl = f >> 6, o = f & 63;
            const float4* wsrc = (const float4*)(wT + (size_t)(k0 + kl) * 64 + o);
            float4 a0 = wsrc[0], a1 = wsrc[1];
            *(float4*)&Wt[kl][o] = a0;
            *(float4*)&Wt[kl][o + 4] = a1;
        }
        // stage Z tile: one k-row entry for 8 consecutive pixels per thread
        {
            int k = k0 + zrow;
            unsigned short v = rc[k];
            int r = v >> 8, c = v & 255;
#pragma unroll
            for (int j = 0; j < 8; ++j) {
                int p = pz + j;
                Zt[zrow][p] = xs[p][r] * xs[p][c];
            }
        }
        __syncthreads();
#pragma unroll
        for (int k = 0; k < 32; ++k) {
            float4 zv = *(const float4*)&Zt[k][pb];
            float4 wv = *(const float4*)&Wt[k][ob];
            float zz[4] = {zv.x, zv.y, zv.z, zv.w};
            float ww[4] = {wv.x, wv.y, wv.z, wv.w};
#pragma unroll
            for (int i = 0; i < 4; ++i)
#pragma unroll
                for (int jj = 0; jj < 4; ++jj)
                    accum[i][jj] = fmaf(zz[i], ww[jj], accum[i][jj]);
        }
    }

#pragma unroll
    for (int i = 0; i < 4; ++i) {
        float4 o4;
        o4.x = accum[i][0] + ctb[ob + 0];
        o4.y = accum[i][1] + ctb[ob + 1];
        o4.z = accum[i][2] + ctb[ob + 2];
        o4.w = accum[i][3] + ctb[ob + 3];
        *(float4*)(A + (size_t)(p0 + pb + i) * 64 + ob) = o4;
    }
}

// G[b,o] = mean over 135 pixels of A
__global__ void f3a_k(const float* __restrict__ A, float* __restrict__ G)
{
    int b = blockIdx.x, o = threadIdx.x;
    float s = 0.f;
    for (int p = 0; p < 135; ++p) s += A[((size_t)b * 135 + p) * 64 + o];
    G[b * 64 + o] = s * (1.0f / 135.0f);
}

// out = xp*(A*(G+1)) + xp
__global__ void f3b_k(const float* __restrict__ xp, const float* __restrict__ A,
                      const float* __restrict__ G, float* __restrict__ out)
{
    int idx = blockIdx.x * 256 + threadIdx.x;
    if (idx >= BATCH * 135 * 64) return;
    int o = idx & 63; int b = idx / (135 * 64);
    float g = G[b * 64 + o];
    float a = A[idx];
    float x = xp[idx];
    out[idx] = fmaf(x, a * (g + 1.f), x);
}

extern "C" void kernel_launch(void* const* d_in, const int* in_sizes, int n_in,
                              void* d_out, int out_size, void* d_ws, size_t ws_size,
                              hipStream_t stream)
{
    const float* x      = (const float*)d_in[0];
    const float* conv_w = (const float*)d_in[2];
    const float* s1_g1  = (const float*)d_in[3];
    const float* s1_b1  = (const float*)d_in[4];
    const float* s1_w1  = (const float*)d_in[5];
    const float* s1_g2  = (const float*)d_in[6];
    const float* s1_b2  = (const float*)d_in[7];
    const float* s1_w2  = (const float*)d_in[8];
    const float* s2_g1  = (const float*)d_in[9];
    const float* s2_b1  = (const float*)d_in[10];
    const float* s2_w1  = (const float*)d_in[11];
    const float* s2_g2  = (const float*)d_in[12];
    const float* s2_b2  = (const float*)d_in[13];
    const float* s2_w2  = (const float*)d_in[14];
    const float* s2_ws  = (const float*)d_in[15];
    const float* s3_g1  = (const float*)d_in[16];
    const float* s3_b1  = (const float*)d_in[17];
    const float* s3_w1  = (const float*)d_in[18];
    const float* s3_g2  = (const float*)d_in[19];
    const float* s3_b2  = (const float*)d_in[20];
    const float* s3_w2  = (const float*)d_in[21];
    const float* s3_ws  = (const float*)d_in[22];
    const float* bn_g   = (const float*)d_in[23];
    const float* bn_b   = (const float*)d_in[24];
    const float* ct_w   = (const float*)d_in[25];
    const float* ct_b   = (const float*)d_in[26];
    float* out = (float*)d_out;

    float* ws  = (float*)d_ws;
    float* h0  = ws;               // (64,16,36,60) 2211840
    float* b1y = h0 + 2211840;     // 2211840
    float* h1  = b1y + 2211840;    // 2211840
    float* b2y = h1 + 2211840;     // (64,32,18,30) 1105920
    float* h2  = b2y + 1105920;    // 1105920
    float* b3y = h2 + 1105920;     // (64,64,9,15) 552960
    float* h3  = b3y + 552960;     // 552960
    float* xp  = h3 + 552960;      // 552960
    float* A   = xp + 552960;      // 552960
    float* G   = A + 552960;       // 4096
    float* wT  = G + 4096;         // 133120
    unsigned short* rc = (unsigned short*)(wT + 133120); // 2080 u16

    dim3 blk(256);

    // stem conv: 3->16, 36x60
    conv3_k<3, 16, 36, 60, 36, 60, 1, false><<<dim3(540, 1), blk, 0, stream>>>(
        x, conv_w, nullptr, nullptr, h0);
    // block1 (stride 1, 16->16)
    conv3_k<16, 16, 36, 60, 36, 60, 1, true><<<dim3(540, 1), blk, 0, stream>>>(
        h0, s1_w1, s1_g1, s1_b1, b1y);
    conv3s_k<16, 16, 16, 36, 60, 1, 1><<<dim3(540, 1), blk, 0, stream>>>(
        b1y, s1_w2, s1_g2, s1_b2, h0, s1_g1, s1_b1, nullptr, h1);
    // block2 (stride 2, 16->32)
    conv3_k<16, 32, 36, 60, 18, 30, 2, true><<<dim3(135, 2), blk, 0, stream>>>(
        h1, s2_w1, s2_g1, s2_b1, b2y);
    conv3s_k<32, 16, 32, 18, 30, 2, 2><<<dim3(135, 2), blk, 0, stream>>>(
        b2y, s2_w2, s2_g2, s2_b2, h1, s2_g1, s2_b1, s2_ws, h2);
    // block3 (stride 2, 32->64)
    conv3_k<32, 64, 18, 30, 9, 15, 2, true><<<dim3(34, 4), blk, 0, stream>>>(
        h2, s3_w1, s3_g1, s3_b1, b3y);
    conv3s_k<64, 32, 64, 9, 15, 2, 2><<<dim3(34, 4), blk, 0, stream>>>(
        b3y, s3_w2, s3_g2, s3_b2, h2, s3_g1, s3_b1, s3_ws, h3);
    // pooling head
    f0_k<<<520, blk, 0, stream>>>(ct_w, wT, rc);
    f1_k<<<2160, blk, 0, stream>>>(h3, bn_g, bn_b, xp);
    f2_k<<<135, blk, 0, stream>>>(xp, wT, rc, ct_b, A);
    f3a_k<<<64, 64, 0, stream>>>(A, G);
    f3b_k<<<2160, blk, 0, stream>>>(xp, A, G, out);
}

// Round 2
// 478.752 us; speedup vs baseline: 1.0548x; 1.0548x over previous
//
#include <hip/hip_runtime.h>

#define BN_S 0.9999950000374997f

constexpr int BATCH = 64;

__device__ __forceinline__ float bnrelu(float x, float gs, float bb) {
    return fmaxf(fmaf(x, gs, bb), 0.f);
}

// 3x3 conv, pad 1, weights staged in LDS. Each thread: one output pixel,
// CO_PER consecutive output channels. blockIdx.y selects the channel group.
// Optional fused BN+ReLU on the input (pad-after-relu == 0, so skipping
// out-of-range taps is exact).
template<int CIN, int COUT, int CO_PER, int HIN, int WIN, int HOUT, int WOUT,
         int STRIDE, bool PRE_BN>
__global__ __launch_bounds__(256) void conv3_k(
    const float* __restrict__ in, const float* __restrict__ w,
    const float* __restrict__ g, const float* __restrict__ bb,
    float* __restrict__ out)
{
    constexpr int NW = CIN * 9 * CO_PER;
    __shared__ float wlds[NW];
    __shared__ float gls[CIN], bls[CIN];
    const int cog = blockIdx.y * CO_PER;

    for (int idx = threadIdx.x; idx < NW; idx += 256) {
        int col = idx % CO_PER; int rest = idx / CO_PER;
        int tap = rest % 9; int ci = rest / 9;
        wlds[idx] = w[((size_t)(cog + col) * CIN + ci) * 9 + tap];
    }
    if (PRE_BN && threadIdx.x < CIN) {
        gls[threadIdx.x] = g[threadIdx.x] * BN_S;
        bls[threadIdx.x] = bb[threadIdx.x];
    }
    __syncthreads();

    const int npix = BATCH * HOUT * WOUT;
    int pix = blockIdx.x * 256 + threadIdx.x;
    if (pix >= npix) return;
    int wo = pix % WOUT; int t = pix / WOUT; int ho = t % HOUT; int b = t / HOUT;

    float acc[CO_PER] = {};
    const int hbase = ho * STRIDE - 1;
    const int wbase = wo * STRIDE - 1;

    for (int ci = 0; ci < CIN; ++ci) {
        float gsv = 0.f, biv = 0.f;
        if constexpr (PRE_BN) { gsv = gls[ci]; biv = bls[ci]; }
        const float* inp = in + ((size_t)(b * CIN + ci)) * (HIN * WIN);
        const float* wrow = wlds + ci * 9 * CO_PER;
#pragma unroll
        for (int dh = 0; dh < 3; ++dh) {
            int hi = hbase + dh;
            if (hi < 0 || hi >= HIN) continue;
#pragma unroll
            for (int dw = 0; dw < 3; ++dw) {
                int wi = wbase + dw;
                if (wi < 0 || wi >= WIN) continue;
                float v = inp[hi * WIN + wi];
                if constexpr (PRE_BN) v = bnrelu(v, gsv, biv);
                const float* wp = wrow + (dh * 3 + dw) * CO_PER;
#pragma unroll
                for (int c4 = 0; c4 < CO_PER; c4 += 4) {
                    float4 wv = *(const float4*)&wp[c4];
                    acc[c4 + 0] = fmaf(v, wv.x, acc[c4 + 0]);
                    acc[c4 + 1] = fmaf(v, wv.y, acc[c4 + 1]);
                    acc[c4 + 2] = fmaf(v, wv.z, acc[c4 + 2]);
                    acc[c4 + 3] = fmaf(v, wv.w, acc[c4 + 3]);
                }
            }
        }
    }
    float* op = out + (((size_t)(b * COUT + cog)) * HOUT + ho) * WOUT + wo;
#pragma unroll
    for (int co = 0; co < CO_PER; ++co)
        op[(size_t)co * HOUT * WOUT] = acc[co];
}

// Second conv of a residual block + shortcut, weights in LDS.
// SC==1: shortcut = bnrelu1(xin) same pixel (identity, CSC==COUT).
// SC==2: shortcut = 1x1-conv(stride SSTR) over bnrelu1(xin), ws[COUT][CSC].
// NHWC_BN: apply final bnrelu(bng,bnb) and write NHWC (b,p,c) instead of NCHW.
template<int CIN, int CSC, int COUT, int CO_PER, int HOUT, int WOUT, int SC,
         int SSTR, bool NHWC_BN>
__global__ __launch_bounds__(256) void conv3s_k(
    const float* __restrict__ y, const float* __restrict__ w2,
    const float* __restrict__ g2, const float* __restrict__ b2,
    const float* __restrict__ xin, const float* __restrict__ g1,
    const float* __restrict__ b1, const float* __restrict__ ws,
    const float* __restrict__ bng, const float* __restrict__ bnb,
    float* __restrict__ out)
{
    constexpr int NW = CIN * 9 * CO_PER;
    constexpr int NWS = (SC == 2) ? CSC * CO_PER : 1;
    __shared__ float wlds[NW];
    __shared__ float wslds[NWS];
    __shared__ float g2ls[CIN], b2ls[CIN];
    __shared__ float g1ls[CSC], b1ls[CSC];
    const int cog = blockIdx.y * CO_PER;

    for (int idx = threadIdx.x; idx < NW; idx += 256) {
        int col = idx % CO_PER; int rest = idx / CO_PER;
        int tap = rest % 9; int ci = rest / 9;
        wlds[idx] = w2[((size_t)(cog + col) * CIN + ci) * 9 + tap];
    }
    if constexpr (SC == 2) {
        for (int idx = threadIdx.x; idx < NWS; idx += 256) {
            int col = idx % CO_PER; int ci = idx / CO_PER;
            wslds[idx] = ws[(size_t)(cog + col) * CSC + ci];
        }
    }
    if (threadIdx.x < CIN) {
        g2ls[threadIdx.x] = g2[threadIdx.x] * BN_S;
        b2ls[threadIdx.x] = b2[threadIdx.x];
    }
    if (threadIdx.x < CSC) {
        g1ls[threadIdx.x] = g1[threadIdx.x] * BN_S;
        b1ls[threadIdx.x] = b1[threadIdx.x];
    }
    __syncthreads();

    const int npix = BATCH * HOUT * WOUT;
    const int HX = HOUT * SSTR, WX = WOUT * SSTR;
    int pix = blockIdx.x * 256 + threadIdx.x;
    if (pix >= npix) return;
    int wo = pix % WOUT; int t = pix / WOUT; int ho = t % HOUT; int b = t / HOUT;

    float acc[CO_PER] = {};

    // main conv: stride 1, input dims = output dims
    for (int ci = 0; ci < CIN; ++ci) {
        float gsv = g2ls[ci], biv = b2ls[ci];
        const float* inp = y + ((size_t)(b * CIN + ci)) * (HOUT * WOUT);
        const float* wrow = wlds + ci * 9 * CO_PER;
#pragma unroll
        for (int dh = 0; dh < 3; ++dh) {
            int hi = ho - 1 + dh;
            if (hi < 0 || hi >= HOUT) continue;
#pragma unroll
            for (int dw = 0; dw < 3; ++dw) {
                int wi = wo - 1 + dw;
                if (wi < 0 || wi >= WOUT) continue;
                float v = bnrelu(inp[hi * WOUT + wi], gsv, biv);
                const float* wp = wrow + (dh * 3 + dw) * CO_PER;
#pragma unroll
                for (int c4 = 0; c4 < CO_PER; c4 += 4) {
                    float4 wv = *(const float4*)&wp[c4];
                    acc[c4 + 0] = fmaf(v, wv.x, acc[c4 + 0]);
                    acc[c4 + 1] = fmaf(v, wv.y, acc[c4 + 1]);
                    acc[c4 + 2] = fmaf(v, wv.z, acc[c4 + 2]);
                    acc[c4 + 3] = fmaf(v, wv.w, acc[c4 + 3]);
                }
            }
        }
    }

    // shortcut
    if constexpr (SC == 1) {
#pragma unroll
        for (int co = 0; co < CO_PER; ++co) {
            int c = cog + co;
            float v = xin[(((size_t)(b * CSC + c)) * HX + ho) * WX + wo];
            acc[co] += bnrelu(v, g1ls[c], b1ls[c]);
        }
    } else {
        for (int ci = 0; ci < CSC; ++ci) {
            float v = bnrelu(xin[(((size_t)(b * CSC + ci)) * HX + ho * SSTR) * WX + wo * SSTR],
                             g1ls[ci], b1ls[ci]);
            const float* wp = wslds + ci * CO_PER;
#pragma unroll
            for (int c4 = 0; c4 < CO_PER; c4 += 4) {
                float4 wv = *(const float4*)&wp[c4];
                acc[c4 + 0] = fmaf(v, wv.x, acc[c4 + 0]);
                acc[c4 + 1] = fmaf(v, wv.y, acc[c4 + 1]);
                acc[c4 + 2] = fmaf(v, wv.z, acc[c4 + 2]);
                acc[c4 + 3] = fmaf(v, wv.w, acc[c4 + 3]);
            }
        }
    }

    if constexpr (NHWC_BN) {
        // fused final bnrelu + channels-last write: out[(b*H*W + p)*64 + c]
        float* op = out + (size_t)pix * 64 + cog;
#pragma unroll
        for (int co = 0; co < CO_PER; ++co)
            op[co] = bnrelu(acc[co], bng[cog + co] * BN_S, bnb[cog + co]);
    } else {
        float* op = out + (((size_t)(b * COUT + cog)) * HOUT + ho) * WOUT + wo;
#pragma unroll
        for (int co = 0; co < CO_PER; ++co)
            op[(size_t)co * HOUT * WOUT] = acc[co];
    }
}

// Prep: transpose ct_w (64,2080) -> wT (2080,64); build (row,col) pair table.
__global__ void f0_k(const float* __restrict__ ctw, float* __restrict__ wT,
                     unsigned short* __restrict__ rc)
{
    int idx = blockIdx.x * 256 + threadIdx.x;
    if (idx < 2080) {
        int r = (int)floorf((129.0f - sqrtf(16641.0f - 8.0f * (float)idx)) * 0.5f);
        if (r < 0) r = 0; if (r > 63) r = 63;
        while (r > 0 && (64 * r - r * (r - 1) / 2) > idx) --r;
        while (r < 63 && (64 * (r + 1) - (r + 1) * r / 2) <= idx) ++r;
        int c = r + (idx - (64 * r - r * (r - 1) / 2));
        rc[idx] = (unsigned short)((r << 8) | c);
    }
    if (idx < 2080 * 64) {
        int k = idx >> 6, o = idx & 63;
        wT[idx] = ctw[o * 2080 + k];
    }
}

// A[p,o] = sum_k xp[p,r_k]*xp[p,c_k] * wT[k,o] + ct_b[o]
// block: 256 threads, 64 pixels x 64 outs, 4x4 micro-tiles, K chunked by 32.
__global__ __launch_bounds__(256) void f2_k(
    const float* __restrict__ xp, const float* __restrict__ wT,
    const unsigned short* __restrict__ rc, const float* __restrict__ ctb,
    float* __restrict__ A)
{
    __shared__ float xs[64][65];
    __shared__ float Zt[32][64];
    __shared__ float Wt[32][64];
    int t = threadIdx.x;
    int p0 = blockIdx.x * 64;

    // stage xp tile (4096 floats, 16 per thread)
    {
        const float4* src = (const float4*)(xp + (size_t)p0 * 64);
#pragma unroll
        for (int j = 0; j < 4; ++j) {
            int f = t * 16 + j * 4;
            float4 v = src[f >> 2];
            int p = f >> 6, c = f & 63;
            xs[p][c] = v.x; xs[p][c + 1] = v.y; xs[p][c + 2] = v.z; xs[p][c + 3] = v.w;
        }
    }

    float accum[4][4] = {};
    const int pb = (t >> 4) * 4, ob = (t & 15) * 4;
    const int zrow = (t * 8) >> 6, pz = (t * 8) & 63;

    for (int k0 = 0; k0 < 2080; k0 += 32) {
        __syncthreads();
        // stage W tile: 8 consecutive floats per thread
        {
            int f = t * 8;
            int kl = f >> 6, o = f & 63;
            const float4* wsrc = (const float4*)(wT + (size_t)(k0 + kl) * 64 + o);
            float4 a0 = wsrc[0], a1 = wsrc[1];
            *(float4*)&Wt[kl][o] = a0;
            *(float4*)&Wt[kl][o + 4] = a1;
        }
        // stage Z tile: one k-row entry for 8 consecutive pixels per thread
        {
            int k = k0 + zrow;
            unsigned short v = rc[k];
            int r = v >> 8, c = v & 255;
#pragma unroll
            for (int j = 0; j < 8; ++j) {
                int p = pz + j;
                Zt[zrow][p] = xs[p][r] * xs[p][c];
            }
        }
        __syncthreads();
#pragma unroll
        for (int k = 0; k < 32; ++k) {
            float4 zv = *(const float4*)&Zt[k][pb];
            float4 wv = *(const float4*)&Wt[k][ob];
            float zz[4] = {zv.x, zv.y, zv.z, zv.w};
            float ww[4] = {wv.x, wv.y, wv.z, wv.w};
#pragma unroll
            for (int i = 0; i < 4; ++i)
#pragma unroll
                for (int jj = 0; jj < 4; ++jj)
                    accum[i][jj] = fmaf(zz[i], ww[jj], accum[i][jj]);
        }
    }

#pragma unroll
    for (int i = 0; i < 4; ++i) {
        float4 o4;
        o4.x = accum[i][0] + ctb[ob + 0];
        o4.y = accum[i][1] + ctb[ob + 1];
        o4.z = accum[i][2] + ctb[ob + 2];
        o4.w = accum[i][3] + ctb[ob + 3];
        *(float4*)(A + (size_t)(p0 + pb + i) * 64 + ob) = o4;
    }
}

// G[b,o] = mean over 135 pixels of A
__global__ void f3a_k(const float* __restrict__ A, float* __restrict__ G)
{
    int b = blockIdx.x, o = threadIdx.x;
    float s = 0.f;
    for (int p = 0; p < 135; ++p) s += A[((size_t)b * 135 + p) * 64 + o];
    G[b * 64 + o] = s * (1.0f / 135.0f);
}

// out = xp*(A*(G+1)) + xp
__global__ void f3b_k(const float* __restrict__ xp, const float* __restrict__ A,
                      const float* __restrict__ G, float* __restrict__ out)
{
    int idx = blockIdx.x * 256 + threadIdx.x;
    if (idx >= BATCH * 135 * 64) return;
    int o = idx & 63; int b = idx / (135 * 64);
    float g = G[b * 64 + o];
    float a = A[idx];
    float x = xp[idx];
    out[idx] = fmaf(x, a * (g + 1.f), x);
}

extern "C" void kernel_launch(void* const* d_in, const int* in_sizes, int n_in,
                              void* d_out, int out_size, void* d_ws, size_t ws_size,
                              hipStream_t stream)
{
    const float* x      = (const float*)d_in[0];
    const float* conv_w = (const float*)d_in[2];
    const float* s1_g1  = (const float*)d_in[3];
    const float* s1_b1  = (const float*)d_in[4];
    const float* s1_w1  = (const float*)d_in[5];
    const float* s1_g2  = (const float*)d_in[6];
    const float* s1_b2  = (const float*)d_in[7];
    const float* s1_w2  = (const float*)d_in[8];
    const float* s2_g1  = (const float*)d_in[9];
    const float* s2_b1  = (const float*)d_in[10];
    const float* s2_w1  = (const float*)d_in[11];
    const float* s2_g2  = (const float*)d_in[12];
    const float* s2_b2  = (const float*)d_in[13];
    const float* s2_w2  = (const float*)d_in[14];
    const float* s2_ws  = (const float*)d_in[15];
    const float* s3_g1  = (const float*)d_in[16];
    const float* s3_b1  = (const float*)d_in[17];
    const float* s3_w1  = (const float*)d_in[18];
    const float* s3_g2  = (const float*)d_in[19];
    const float* s3_b2  = (const float*)d_in[20];
    const float* s3_w2  = (const float*)d_in[21];
    const float* s3_ws  = (const float*)d_in[22];
    const float* bn_g   = (const float*)d_in[23];
    const float* bn_b   = (const float*)d_in[24];
    const float* ct_w   = (const float*)d_in[25];
    const float* ct_b   = (const float*)d_in[26];
    float* out = (float*)d_out;

    float* ws  = (float*)d_ws;
    float* h0  = ws;               // (64,16,36,60) 2211840
    float* b1y = h0 + 2211840;     // 2211840
    float* h1  = b1y + 2211840;    // 2211840
    float* b2y = h1 + 2211840;     // (64,32,18,30) 1105920
    float* h2  = b2y + 1105920;    // 1105920
    float* b3y = h2 + 1105920;     // (64,64,9,15) 552960
    float* xp  = b3y + 552960;     // (64,135,64) NHWC, written by fused conv3s
    float* A   = xp + 552960;      // 552960
    float* G   = A + 552960;       // 4096
    float* wT  = G + 4096;         // 133120
    unsigned short* rc = (unsigned short*)(wT + 133120); // 2080 u16

    dim3 blk(256);

    // stem conv: 3->16, 36x60
    conv3_k<3, 16, 16, 36, 60, 36, 60, 1, false><<<dim3(540, 1), blk, 0, stream>>>(
        x, conv_w, nullptr, nullptr, h0);
    // block1 (stride 1, 16->16)
    conv3_k<16, 16, 16, 36, 60, 36, 60, 1, true><<<dim3(540, 1), blk, 0, stream>>>(
        h0, s1_w1, s1_g1, s1_b1, b1y);
    conv3s_k<16, 16, 16, 16, 36, 60, 1, 1, false><<<dim3(540, 1), blk, 0, stream>>>(
        b1y, s1_w2, s1_g2, s1_b2, h0, s1_g1, s1_b1, nullptr, nullptr, nullptr, h1);
    // block2 (stride 2, 16->32)
    conv3_k<16, 32, 8, 36, 60, 18, 30, 2, true><<<dim3(135, 4), blk, 0, stream>>>(
        h1, s2_w1, s2_g1, s2_b1, b2y);
    conv3s_k<32, 16, 32, 8, 18, 30, 2, 2, false><<<dim3(135, 4), blk, 0, stream>>>(
        b2y, s2_w2, s2_g2, s2_b2, h1, s2_g1, s2_b1, s2_ws, nullptr, nullptr, h2);
    // block3 (stride 2, 32->64)
    conv3_k<32, 64, 8, 18, 30, 9, 15, 2, true><<<dim3(34, 8), blk, 0, stream>>>(
        h2, s3_w1, s3_g1, s3_b1, b3y);
    // fused: conv + shortcut + final bnrelu + NHWC transpose -> xp
    conv3s_k<64, 32, 64, 8, 9, 15, 2, 2, true><<<dim3(34, 8), blk, 0, stream>>>(
        b3y, s3_w2, s3_g2, s3_b2, h2, s3_g1, s3_b1, s3_ws, bn_g, bn_b, xp);
    // pooling head
    f0_k<<<520, blk, 0, stream>>>(ct_w, wT, rc);
    f2_k<<<135, blk, 0, stream>>>(xp, wT, rc, ct_b, A);
    f3a_k<<<64, 64, 0, stream>>>(A, G);
    f3b_k<<<2160, blk, 0, stream>>>(xp, A, G, out);
}

// Round 3
// 289.089 us; speedup vs baseline: 1.7469x; 1.6561x over previous
//
#include <hip/hip_runtime.h>

#define BN_S 0.9999950000374997f

constexpr int BATCH = 64;

__device__ __forceinline__ float bnrelu(float x, float gs, float bb) {
    return fmaxf(fmaf(x, gs, bb), 0.f);
}

// Generic fused conv3x3 (pad 1) with:
//  - activations staged (bnrelu'd, zero-padded) in LDS per block
//  - weights staged in LDS
//  - register tile: P horizontal pixels x CO_PER output channels per thread
//  - CIN split into CICH chunks over blockIdx.z; partial sums written to
//    out + zci*out_pstride (PARTS inputs summed at staging for chained splits)
//  - optional shortcut (SC=1 identity, SC=2 1x1-conv stride SSTR) added by
//    chunk 0 only
template<int CIN, int CICH, int COUT, int CO_PER, int HIN, int WIN,
         int HOUT, int WOUT, int STRIDE, int ROWS, int P, int PARTS,
         bool PRE_BN, int SC, int CSC, int SSTR>
__global__ __launch_bounds__(256) void convT_k(
    const float* __restrict__ in, size_t in_pstride,
    const float* __restrict__ w,
    const float* __restrict__ g, const float* __restrict__ bb,
    const float* __restrict__ xin,
    const float* __restrict__ g1v, const float* __restrict__ b1v,
    const float* __restrict__ wsc,
    float* __restrict__ out, size_t out_pstride)
{
    constexpr int IR = (STRIDE == 1) ? ROWS + 2 : 2 * ROWS + 1;
    constexpr int TW = (STRIDE == 1) ? WIN + 2 : WIN + 1;
    constexpr int AW = (P - 1) * STRIDE + 3;
    constexpr int NCOG = COUT / CO_PER;
    constexpr int PGW = WOUT / P;
    constexpr int NG = ROWS * PGW;
    constexpr int NITEMS = NG * NCOG;

    __shared__ float xs[CICH * IR * TW];
    __shared__ float wlds[CICH * 9 * COUT];
    __shared__ float g1l[SC ? CSC : 1], b1l[SC ? CSC : 1];
    __shared__ float wscl[(SC == 2) ? CSC * COUT : 1];

    const int band = blockIdx.x, b = blockIdx.y, zci = blockIdx.z;
    const int ci0 = zci * CICH;
    const int r0 = band * ROWS;
    const int r0in = r0 * STRIDE - 1;
    const int tid = threadIdx.x;

    // stage weights: wlds[ci][tap][co]
    for (int i = tid; i < CICH * 9 * COUT; i += 256) {
        int co = i % COUT; int rem = i / COUT; int tap = rem % 9; int ci = rem / 9;
        wlds[i] = w[((size_t)co * CIN + ci0 + ci) * 9 + tap];
    }
    if constexpr (SC != 0) {
        if (tid < CSC) { g1l[tid] = g1v[tid] * BN_S; b1l[tid] = b1v[tid]; }
        if constexpr (SC == 2) {
            for (int i = tid; i < CSC * COUT; i += 256) {
                int co = i % COUT; int ci = i / COUT;
                wscl[i] = wsc[(size_t)co * CSC + ci];
            }
        }
    }
    // stage activations (sum PARTS partials, bnrelu, zero pad)
    for (int i = tid; i < CICH * IR * TW; i += 256) {
        int cc = i % TW; int rem = i / TW; int rr = rem % IR; int ci = rem / IR;
        int gr = r0in + rr; int gc = cc - 1;
        float v = 0.f;
        if (gr >= 0 && gr < HIN && gc >= 0 && gc < WIN) {
            size_t off = ((size_t)(b * CIN + ci0 + ci) * HIN + gr) * WIN + gc;
            v = in[off];
            if constexpr (PARTS >= 2) v += in[off + in_pstride];
            if constexpr (PARTS >= 3) v += in[off + 2 * in_pstride];
            if constexpr (PARTS >= 4) v += in[off + 3 * in_pstride];
            if constexpr (PRE_BN) v = bnrelu(v, g[ci0 + ci] * BN_S, bb[ci0 + ci]);
        }
        xs[i] = v;
    }
    __syncthreads();

    for (int it = tid; it < NITEMS; it += 256) {
        const int cog = it / NG; const int gi = it % NG;
        const int lr = gi / PGW; const int wc = (gi % PGW) * P;
        float acc[P][CO_PER];
#pragma unroll
        for (int j = 0; j < P; ++j)
#pragma unroll
            for (int co = 0; co < CO_PER; ++co) acc[j][co] = 0.f;

        for (int ci = 0; ci < CICH; ++ci) {
            const float* xb = xs + ((ci * IR) + lr * STRIDE) * TW + wc * STRIDE;
#pragma unroll
            for (int dh = 0; dh < 3; ++dh) {
                float aw[AW];
#pragma unroll
                for (int a = 0; a < AW; ++a) aw[a] = xb[dh * TW + a];
#pragma unroll
                for (int dw = 0; dw < 3; ++dw) {
                    const float* wp = wlds + (ci * 9 + dh * 3 + dw) * COUT + cog * CO_PER;
#pragma unroll
                    for (int c4 = 0; c4 < CO_PER; c4 += 4) {
                        float4 wv = *(const float4*)(wp + c4);
#pragma unroll
                        for (int j = 0; j < P; ++j) {
                            float a_ = aw[j * STRIDE + dw];
                            acc[j][c4 + 0] = fmaf(a_, wv.x, acc[j][c4 + 0]);
                            acc[j][c4 + 1] = fmaf(a_, wv.y, acc[j][c4 + 1]);
                            acc[j][c4 + 2] = fmaf(a_, wv.z, acc[j][c4 + 2]);
                            acc[j][c4 + 3] = fmaf(a_, wv.w, acc[j][c4 + 3]);
                        }
                    }
                }
            }
        }

        if constexpr (SC == 1) {
            if (zci == 0) {
#pragma unroll
                for (int co = 0; co < CO_PER; ++co) {
                    int c = cog * CO_PER + co;
#pragma unroll
                    for (int j = 0; j < P; ++j) {
                        float v = xin[((size_t)(b * CSC + c) * HOUT + (r0 + lr)) * WOUT + wc + j];
                        acc[j][co] += bnrelu(v, g1l[c], b1l[c]);
                    }
                }
            }
        }
        if constexpr (SC == 2) {
            if (zci == 0) {
                const int hix = (r0 + lr) * SSTR;
                for (int ci = 0; ci < CSC; ++ci) {
                    float vv[P];
#pragma unroll
                    for (int j = 0; j < P; ++j)
                        vv[j] = bnrelu(xin[((size_t)(b * CSC + ci) * (HOUT * SSTR) + hix) * (WOUT * SSTR)
                                           + (wc + j) * SSTR], g1l[ci], b1l[ci]);
                    const float* wp = wscl + ci * COUT + cog * CO_PER;
#pragma unroll
                    for (int c4 = 0; c4 < CO_PER; c4 += 4) {
                        float4 wv = *(const float4*)(wp + c4);
#pragma unroll
                        for (int j = 0; j < P; ++j) {
                            acc[j][c4 + 0] = fmaf(vv[j], wv.x, acc[j][c4 + 0]);
                            acc[j][c4 + 1] = fmaf(vv[j], wv.y, acc[j][c4 + 1]);
                            acc[j][c4 + 2] = fmaf(vv[j], wv.z, acc[j][c4 + 2]);
                            acc[j][c4 + 3] = fmaf(vv[j], wv.w, acc[j][c4 + 3]);
                        }
                    }
                }
            }
        }

        float* op = out + (size_t)zci * out_pstride
                    + ((size_t)(b * COUT + cog * CO_PER) * HOUT + (r0 + lr)) * WOUT + wc;
#pragma unroll
        for (int co = 0; co < CO_PER; ++co)
#pragma unroll
            for (int j = 0; j < P; ++j)
                op[(size_t)co * HOUT * WOUT + j] = acc[j][co];
    }
}

// Prep: transpose ct_w (64,2080) -> wT (2080,64); build (row,col) pair table.
__global__ void f0_k(const float* __restrict__ ctw, float* __restrict__ wT,
                     unsigned short* __restrict__ rc)
{
    int idx = blockIdx.x * 256 + threadIdx.x;
    if (idx < 2080) {
        int r = (int)floorf((129.0f - sqrtf(16641.0f - 8.0f * (float)idx)) * 0.5f);
        if (r < 0) r = 0; if (r > 63) r = 63;
        while (r > 0 && (64 * r - r * (r - 1) / 2) > idx) --r;
        while (r < 63 && (64 * (r + 1) - (r + 1) * r / 2) <= idx) ++r;
        int c = r + (idx - (64 * r - r * (r - 1) / 2));
        rc[idx] = (unsigned short)((r << 8) | c);
    }
    if (idx < 2080 * 64) {
        int k = idx >> 6, o = idx & 63;
        wT[idx] = ctw[o * 2080 + k];
    }
}

// Reduce b3c2: sum 8 conv partials + 1x1 shortcut over bnrelu1(h2=p0+p1)
// + final bnrelu(bn_g,bn_b), write xp NHWC. idx in NCHW order for coalesced
// partial reads.
__global__ __launch_bounds__(256) void red_k(
    const float* __restrict__ pb, const float* __restrict__ h2a,
    const float* __restrict__ h2b, const float* __restrict__ g1,
    const float* __restrict__ b1, const float* __restrict__ wsc,
    const float* __restrict__ bng, const float* __restrict__ bnb,
    float* __restrict__ xp)
{
    __shared__ float wscl[32 * 64];  // [ci][c]
    __shared__ float g1l[32], b1l[32];
    int t = threadIdx.x;
    for (int i = t; i < 2048; i += 256) {
        int c = i & 63; int ci = i >> 6;
        wscl[i] = wsc[(size_t)c * 32 + ci];
    }
    if (t < 32) { g1l[t] = g1[t] * BN_S; b1l[t] = b1[t]; }
    __syncthreads();

    int idx = blockIdx.x * 256 + t;          // (b*64 + c)*135 + p
    int p = idx % 135; int rem = idx / 135; int c = rem & 63; int b = rem >> 6;
    float y = 0.f;
#pragma unroll
    for (int q = 0; q < 8; ++q) y += pb[idx + (size_t)q * 552960];
    int hp = p / 15, wp = p % 15;
    float sc = 0.f;
    for (int ci = 0; ci < 32; ++ci) {
        size_t off = ((size_t)(b * 32 + ci) * 18 + hp * 2) * 30 + wp * 2;
        float hv = h2a[off] + h2b[off];
        sc = fmaf(bnrelu(hv, g1l[ci], b1l[ci]), wscl[ci * 64 + c], sc);
    }
    float v = y + sc;
    xp[((size_t)b * 135 + p) * 64 + c] = bnrelu(v, bng[c] * BN_S, bnb[c]);
}

// A_q[p,o] = sum_{k in quarter q} xp[p,r_k]*xp[p,c_k] * wT[k,o] (+ct_b if q==0)
// block: 64 pixels x 64 outs, thread = 4pix x 4out; grid (135, 4).
__global__ __launch_bounds__(256) void f2_k(
    const float* __restrict__ xp, const float* __restrict__ wT,
    const unsigned short* __restrict__ rc, const float* __restrict__ ctb,
    float* __restrict__ Abase)
{
    __shared__ float xs[64][65];
    __shared__ float Zt[32][64];
    __shared__ float Wt[32][64];
    const int t = threadIdx.x;
    const int p0 = blockIdx.x * 64;
    const int kq = blockIdx.y;
    const int kstart = (kq == 0) ? 0 : 544 + (kq - 1) * 512;
    const int kend = kstart + ((kq == 0) ? 544 : 512);
    float* A = Abase + (size_t)kq * 552960;

    {
        const float4* src = (const float4*)(xp + (size_t)p0 * 64);
#pragma unroll
        for (int j = 0; j < 4; ++j) {
            int f = t * 16 + j * 4;
            float4 v = src[f >> 2];
            int p = f >> 6, c = f & 63;
            xs[p][c] = v.x; xs[p][c + 1] = v.y; xs[p][c + 2] = v.z; xs[p][c + 3] = v.w;
        }
    }

    float accum[4][4] = {};
    const int pr = t >> 4;            // 16 pixel-quads
    const int oc = (t & 15) * 4;      // 16 out-quads
    const int zrow = t >> 3;          // 32 z-rows
    const int pz = (t & 7) * 8;       // 8 pixels per thread

    for (int k0 = kstart; k0 < kend; k0 += 32) {
        __syncthreads();
        {   // W tile
            int f = t * 8;
            int kl = f >> 6, o = f & 63;
            const float4* wsrc = (const float4*)(wT + (size_t)(k0 + kl) * 64 + o);
            float4 a0 = wsrc[0], a1 = wsrc[1];
            *(float4*)&Wt[kl][o] = a0;
            *(float4*)&Wt[kl][o + 4] = a1;
        }
        {   // Z tile
            unsigned short v = rc[k0 + zrow];
            int r = v >> 8, c = v & 255;
#pragma unroll
            for (int j = 0; j < 8; ++j) {
                int p = pz + j;
                Zt[zrow][p] = xs[p][r] * xs[p][c];
            }
        }
        __syncthreads();
#pragma unroll
        for (int k = 0; k < 32; ++k) {
            float4 zv = *(const float4*)&Zt[k][pr * 4];
            float4 wv = *(const float4*)&Wt[k][oc];
            float zz[4] = {zv.x, zv.y, zv.z, zv.w};
            float ww[4] = {wv.x, wv.y, wv.z, wv.w};
#pragma unroll
            for (int i = 0; i < 4; ++i)
#pragma unroll
                for (int jj = 0; jj < 4; ++jj)
                    accum[i][jj] = fmaf(zz[i], ww[jj], accum[i][jj]);
        }
    }

#pragma unroll
    for (int i = 0; i < 4; ++i) {
        float4 o4;
        o4.x = accum[i][0]; o4.y = accum[i][1]; o4.z = accum[i][2]; o4.w = accum[i][3];
        if (kq == 0) { o4.x += ctb[oc]; o4.y += ctb[oc + 1]; o4.z += ctb[oc + 2]; o4.w += ctb[oc + 3]; }
        *(float4*)(A + (size_t)(p0 + pr * 4 + i) * 64 + oc) = o4;
    }
}

// G[b,o] = mean over 135 pixels of sum of 4 A partials
__global__ void f3a_k(const float* __restrict__ A, float* __restrict__ G)
{
    int b = blockIdx.x; int t = threadIdx.x;
    int o = t & 63; int grp = t >> 6;
    float s = 0.f;
    for (int p = grp; p < 135; p += 4) {
        size_t off = ((size_t)b * 135 + p) * 64 + o;
        s += A[off] + A[off + 552960] + A[off + 2 * 552960] + A[off + 3 * 552960];
    }
    __shared__ float red[4][64];
    red[grp][o] = s;
    __syncthreads();
    if (t < 64) G[b * 64 + t] = (red[0][t] + red[1][t] + red[2][t] + red[3][t]) * (1.0f / 135.0f);
}

// out = xp*(A*(G+1)) + xp, A = sum of 4 partials
__global__ void f3b_k(const float* __restrict__ xp, const float* __restrict__ A,
                      const float* __restrict__ G, float* __restrict__ out)
{
    int idx = blockIdx.x * 256 + threadIdx.x;
    if (idx >= BATCH * 135 * 64) return;
    int o = idx & 63; int b = idx / (135 * 64);
    float a = A[idx] + A[idx + 552960] + A[idx + 2 * 552960] + A[idx + 3 * 552960];
    float g = G[b * 64 + o];
    float x = xp[idx];
    out[idx] = fmaf(x, a * (g + 1.f), x);
}

extern "C" void kernel_launch(void* const* d_in, const int* in_sizes, int n_in,
                              void* d_out, int out_size, void* d_ws, size_t ws_size,
                              hipStream_t stream)
{
    const float* x      = (const float*)d_in[0];
    const float* conv_w = (const float*)d_in[2];
    const float* s1_g1  = (const float*)d_in[3];
    const float* s1_b1  = (const float*)d_in[4];
    const float* s1_w1  = (const float*)d_in[5];
    const float* s1_g2  = (const float*)d_in[6];
    const float* s1_b2  = (const float*)d_in[7];
    const float* s1_w2  = (const float*)d_in[8];
    const float* s2_g1  = (const float*)d_in[9];
    const float* s2_b1  = (const float*)d_in[10];
    const float* s2_w1  = (const float*)d_in[11];
    const float* s2_g2  = (const float*)d_in[12];
    const float* s2_b2  = (const float*)d_in[13];
    const float* s2_w2  = (const float*)d_in[14];
    const float* s2_ws  = (const float*)d_in[15];
    const float* s3_g1  = (const float*)d_in[16];
    const float* s3_b1  = (const float*)d_in[17];
    const float* s3_w1  = (const float*)d_in[18];
    const float* s3_g2  = (const float*)d_in[19];
    const float* s3_b2  = (const float*)d_in[20];
    const float* s3_w2  = (const float*)d_in[21];
    const float* s3_ws  = (const float*)d_in[22];
    const float* bn_g   = (const float*)d_in[23];
    const float* bn_b   = (const float*)d_in[24];
    const float* ct_w   = (const float*)d_in[25];
    const float* ct_b   = (const float*)d_in[26];
    float* out = (float*)d_out;

    float* ws = (float*)d_ws;
    // region plan (floats), aggressive sequential reuse (total ~44.8MB):
    float* h0      = ws + 0;         // [0, 2211840)            stem .. b1c2
    float* p_b1c1  = ws + 2211840;   // 2x2211840 [2211840, 6635520)  b1c1 .. b1c2
    float* h1      = ws + 6635520;   // [6635520, 8847360)      b1c2 .. b2c2
    float* p_b2c1  = ws + 2211840;   // 2x1105920 (reuse)       b2c1 .. b2c2
    float* p_b2c2  = ws + 8847360;   // 2x1105920 [8847360, 11059200) b2c2 .. red
    float* p_b3c1  = ws + 2211840;   // 4x552960 (reuse)        b3c1 .. b3c2
    float* p_b3c2  = ws + 4423680;   // 8x552960 [4423680, 8847360) (reuse) b3c2 .. red
    float* xp      = ws + 0;         // [0, 552960)  (reuse h0) red .. f3b
    float* A       = ws + 552960;    // 4x552960 [552960, 2764800) (reuse) f2 .. f3b
    float* G       = ws + 11059200;  // 4096
    float* wT      = ws + 11063296;  // 133120
    unsigned short* rc = (unsigned short*)(ws + 11196416); // 2080 u16

    dim3 blk(256);

    f0_k<<<520, blk, 0, stream>>>(ct_w, wT, rc);

    // stem: 3->16, 36x60, no pre-BN
    convT_k<3, 3, 16, 16, 36, 60, 36, 60, 1, 18, 5, 1, false, 0, 1, 1>
        <<<dim3(2, 64, 1), blk, 0, stream>>>(
        x, 0, conv_w, nullptr, nullptr, nullptr, nullptr, nullptr, nullptr, h0, 0);
    // b1c1: bnrelu(s1_g1) -> conv 16->16, ci split 8x2
    convT_k<16, 8, 16, 8, 36, 60, 36, 60, 1, 9, 5, 1, true, 0, 1, 1>
        <<<dim3(4, 64, 2), blk, 0, stream>>>(
        h0, 0, s1_w1, s1_g1, s1_b1, nullptr, nullptr, nullptr, nullptr, p_b1c1, 2211840);
    // b1c2: sum 2 partials, bnrelu(s1_g2) -> conv + identity shortcut(h0,s1_g1)
    convT_k<16, 16, 16, 8, 36, 60, 36, 60, 1, 9, 5, 2, true, 1, 16, 1>
        <<<dim3(4, 64, 1), blk, 0, stream>>>(
        p_b1c1, 2211840, s1_w2, s1_g2, s1_b2, h0, s1_g1, s1_b1, nullptr, h1, 0);
    // b2c1: bnrelu(s2_g1) -> conv 16->32 stride2, ci split 8x2
    convT_k<16, 8, 32, 8, 36, 60, 18, 30, 2, 9, 5, 1, true, 0, 1, 1>
        <<<dim3(2, 64, 2), blk, 0, stream>>>(
        h1, 0, s2_w1, s2_g1, s2_b1, nullptr, nullptr, nullptr, nullptr, p_b2c1, 1105920);
    // b2c2: sum 2, bnrelu(s2_g2) -> conv 32->32, ci split 16x2, + 1x1 sc(h1,s2_g1)
    convT_k<32, 16, 32, 8, 18, 30, 18, 30, 1, 9, 5, 2, true, 2, 16, 2>
        <<<dim3(2, 64, 2), blk, 0, stream>>>(
        p_b2c1, 1105920, s2_w2, s2_g2, s2_b2, h1, s2_g1, s2_b1, s2_ws, p_b2c2, 1105920);
    // b3c1: sum 2, bnrelu(s3_g1) -> conv 32->64 stride2, ci split 8x4
    convT_k<32, 8, 64, 8, 18, 30, 9, 15, 2, 9, 5, 2, true, 0, 1, 1>
        <<<dim3(1, 64, 4), blk, 0, stream>>>(
        p_b2c2, 1105920, s3_w1, s3_g1, s3_b1, nullptr, nullptr, nullptr, nullptr, p_b3c1, 552960);
    // b3c2: sum 4, bnrelu(s3_g2) -> conv 64->64, ci split 8x8 (shortcut in red)
    convT_k<64, 8, 64, 8, 9, 15, 9, 15, 1, 9, 5, 4, true, 0, 1, 1>
        <<<dim3(1, 64, 8), blk, 0, stream>>>(
        p_b3c1, 552960, s3_w2, s3_g2, s3_b2, nullptr, nullptr, nullptr, nullptr, p_b3c2, 552960);
    // reduce: 8 partials + 1x1 sc(bnrelu1(h2=p0+p1)) + final bn -> xp (NHWC)
    red_k<<<2160, blk, 0, stream>>>(p_b3c2, p_b2c2, p_b2c2 + 1105920,
                                    s3_g1, s3_b1, s3_ws, bn_g, bn_b, xp);
    // pooling head: A partials over 4 K-quarters
    f2_k<<<dim3(135, 4), blk, 0, stream>>>(xp, wT, rc, ct_b, A);
    f3a_k<<<64, blk, 0, stream>>>(A, G);
    f3b_k<<<2160, blk, 0, stream>>>(xp, A, G, out);
}

// Round 4
// 270.504 us; speedup vs baseline: 1.8669x; 1.0687x over previous
//
#include <hip/hip_runtime.h>

#define BN_S 0.9999950000374997f

constexpr int BATCH = 64;

typedef __attribute__((ext_vector_type(8))) short bf16x8;
typedef __attribute__((ext_vector_type(4))) float f32x4;

__device__ __forceinline__ float bnrelu(float x, float gs, float bb) {
    return fmaxf(fmaf(x, gs, bb), 0.f);
}

__device__ __forceinline__ unsigned short f2bf(float f) {
    unsigned u = __builtin_bit_cast(unsigned, f);
    return (unsigned short)((u + 0x7FFFu + ((u >> 16) & 1u)) >> 16);
}
__device__ __forceinline__ float bf2f(unsigned short h) {
    unsigned u = ((unsigned)h) << 16;
    return __builtin_bit_cast(float, u);
}

// ---------------- convs (unchanged from round 3) ----------------
template<int CIN, int CICH, int COUT, int CO_PER, int HIN, int WIN,
         int HOUT, int WOUT, int STRIDE, int ROWS, int P, int PARTS,
         bool PRE_BN, int SC, int CSC, int SSTR>
__global__ __launch_bounds__(256) void convT_k(
    const float* __restrict__ in, size_t in_pstride,
    const float* __restrict__ w,
    const float* __restrict__ g, const float* __restrict__ bb,
    const float* __restrict__ xin,
    const float* __restrict__ g1v, const float* __restrict__ b1v,
    const float* __restrict__ wsc,
    float* __restrict__ out, size_t out_pstride)
{
    constexpr int IR = (STRIDE == 1) ? ROWS + 2 : 2 * ROWS + 1;
    constexpr int TW = (STRIDE == 1) ? WIN + 2 : WIN + 1;
    constexpr int AW = (P - 1) * STRIDE + 3;
    constexpr int NCOG = COUT / CO_PER;
    constexpr int PGW = WOUT / P;
    constexpr int NG = ROWS * PGW;
    constexpr int NITEMS = NG * NCOG;

    __shared__ float xs[CICH * IR * TW];
    __shared__ float wlds[CICH * 9 * COUT];
    __shared__ float g1l[SC ? CSC : 1], b1l[SC ? CSC : 1];
    __shared__ float wscl[(SC == 2) ? CSC * COUT : 1];

    const int band = blockIdx.x, b = blockIdx.y, zci = blockIdx.z;
    const int ci0 = zci * CICH;
    const int r0 = band * ROWS;
    const int r0in = r0 * STRIDE - 1;
    const int tid = threadIdx.x;

    for (int i = tid; i < CICH * 9 * COUT; i += 256) {
        int co = i % COUT; int rem = i / COUT; int tap = rem % 9; int ci = rem / 9;
        wlds[i] = w[((size_t)co * CIN + ci0 + ci) * 9 + tap];
    }
    if constexpr (SC != 0) {
        if (tid < CSC) { g1l[tid] = g1v[tid] * BN_S; b1l[tid] = b1v[tid]; }
        if constexpr (SC == 2) {
            for (int i = tid; i < CSC * COUT; i += 256) {
                int co = i % COUT; int ci = i / COUT;
                wscl[i] = wsc[(size_t)co * CSC + ci];
            }
        }
    }
    for (int i = tid; i < CICH * IR * TW; i += 256) {
        int cc = i % TW; int rem = i / TW; int rr = rem % IR; int ci = rem / IR;
        int gr = r0in + rr; int gc = cc - 1;
        float v = 0.f;
        if (gr >= 0 && gr < HIN && gc >= 0 && gc < WIN) {
            size_t off = ((size_t)(b * CIN + ci0 + ci) * HIN + gr) * WIN + gc;
            v = in[off];
            if constexpr (PARTS >= 2) v += in[off + in_pstride];
            if constexpr (PARTS >= 3) v += in[off + 2 * in_pstride];
            if constexpr (PARTS >= 4) v += in[off + 3 * in_pstride];
            if constexpr (PRE_BN) v = bnrelu(v, g[ci0 + ci] * BN_S, bb[ci0 + ci]);
        }
        xs[i] = v;
    }
    __syncthreads();

    for (int it = tid; it < NITEMS; it += 256) {
        const int cog = it / NG; const int gi = it % NG;
        const int lr = gi / PGW; const int wc = (gi % PGW) * P;
        float acc[P][CO_PER];
#pragma unroll
        for (int j = 0; j < P; ++j)
#pragma unroll
            for (int co = 0; co < CO_PER; ++co) acc[j][co] = 0.f;

        for (int ci = 0; ci < CICH; ++ci) {
            const float* xb = xs + ((ci * IR) + lr * STRIDE) * TW + wc * STRIDE;
#pragma unroll
            for (int dh = 0; dh < 3; ++dh) {
                float aw[AW];
#pragma unroll
                for (int a = 0; a < AW; ++a) aw[a] = xb[dh * TW + a];
#pragma unroll
                for (int dw = 0; dw < 3; ++dw) {
                    const float* wp = wlds + (ci * 9 + dh * 3 + dw) * COUT + cog * CO_PER;
#pragma unroll
                    for (int c4 = 0; c4 < CO_PER; c4 += 4) {
                        float4 wv = *(const float4*)(wp + c4);
#pragma unroll
                        for (int j = 0; j < P; ++j) {
                            float a_ = aw[j * STRIDE + dw];
                            acc[j][c4 + 0] = fmaf(a_, wv.x, acc[j][c4 + 0]);
                            acc[j][c4 + 1] = fmaf(a_, wv.y, acc[j][c4 + 1]);
                            acc[j][c4 + 2] = fmaf(a_, wv.z, acc[j][c4 + 2]);
                            acc[j][c4 + 3] = fmaf(a_, wv.w, acc[j][c4 + 3]);
                        }
                    }
                }
            }
        }

        if constexpr (SC == 1) {
            if (zci == 0) {
#pragma unroll
                for (int co = 0; co < CO_PER; ++co) {
                    int c = cog * CO_PER + co;
#pragma unroll
                    for (int j = 0; j < P; ++j) {
                        float v = xin[((size_t)(b * CSC + c) * HOUT + (r0 + lr)) * WOUT + wc + j];
                        acc[j][co] += bnrelu(v, g1l[c], b1l[c]);
                    }
                }
            }
        }
        if constexpr (SC == 2) {
            if (zci == 0) {
                const int hix = (r0 + lr) * SSTR;
                for (int ci = 0; ci < CSC; ++ci) {
                    float vv[P];
#pragma unroll
                    for (int j = 0; j < P; ++j)
                        vv[j] = bnrelu(xin[((size_t)(b * CSC + ci) * (HOUT * SSTR) + hix) * (WOUT * SSTR)
                                           + (wc + j) * SSTR], g1l[ci], b1l[ci]);
                    const float* wp = wscl + ci * COUT + cog * CO_PER;
#pragma unroll
                    for (int c4 = 0; c4 < CO_PER; c4 += 4) {
                        float4 wv = *(const float4*)(wp + c4);
#pragma unroll
                        for (int j = 0; j < P; ++j) {
                            acc[j][c4 + 0] = fmaf(vv[j], wv.x, acc[j][c4 + 0]);
                            acc[j][c4 + 1] = fmaf(vv[j], wv.y, acc[j][c4 + 1]);
                            acc[j][c4 + 2] = fmaf(vv[j], wv.z, acc[j][c4 + 2]);
                            acc[j][c4 + 3] = fmaf(vv[j], wv.w, acc[j][c4 + 3]);
                        }
                    }
                }
            }
        }

        float* op = out + (size_t)zci * out_pstride
                    + ((size_t)(b * COUT + cog * CO_PER) * HOUT + (r0 + lr)) * WOUT + wc;
#pragma unroll
        for (int co = 0; co < CO_PER; ++co)
#pragma unroll
            for (int j = 0; j < P; ++j)
                op[(size_t)co * HOUT * WOUT + j] = acc[j][co];
    }
}

// ---------------- Wfrag prep ----------------
// Pack ct_w (64,2080) into bf16 MFMA B-fragments, grouped by column c of the
// 64x64 symmetric-upper pairing. Slot s: c<32 -> s=c (1 chunk); c>=32 ->
// s=2c-32+ch (2 chunks). Element: wf[((s*4 + tile)*64 + lane)*8 + j] =
// B[k][o], k = ch*32 + (lane>>4)*8 + j, o = tile*16 + (lane&15),
// B[k][o] = (k<=c) ? ct_w[o][k*(129-k)/2 + (c-k)] : 0.
__global__ void f0_k(const float* __restrict__ ctw, short* __restrict__ wf)
{
    int id = blockIdx.x * 256 + threadIdx.x;   // < 196608
    int j = id & 7; int lane = (id >> 3) & 63; int tile = (id >> 9) & 3; int s = id >> 11;
    int c, ch;
    if (s < 32) { c = s; ch = 0; }
    else { c = 32 + ((s - 32) >> 1); ch = (s - 32) & 1; }
    int k = ch * 32 + ((lane >> 4) << 3) + j;
    int o = tile * 16 + (lane & 15);
    float val = 0.f;
    if (k <= c) val = ctw[o * 2080 + (k * (129 - k)) / 2 + (c - k)];
    wf[id] = (short)f2bf(val);
}

// ---------------- reduce b3c2 -> xp (unchanged) ----------------
__global__ __launch_bounds__(256) void red_k(
    const float* __restrict__ pb, const float* __restrict__ h2a,
    const float* __restrict__ h2b, const float* __restrict__ g1,
    const float* __restrict__ b1, const float* __restrict__ wsc,
    const float* __restrict__ bng, const float* __restrict__ bnb,
    float* __restrict__ xp)
{
    __shared__ float wscl[32 * 64];
    __shared__ float g1l[32], b1l[32];
    int t = threadIdx.x;
    for (int i = t; i < 2048; i += 256) {
        int c = i & 63; int ci = i >> 6;
        wscl[i] = wsc[(size_t)c * 32 + ci];
    }
    if (t < 32) { g1l[t] = g1[t] * BN_S; b1l[t] = b1[t]; }
    __syncthreads();

    int idx = blockIdx.x * 256 + t;
    int p = idx % 135; int rem = idx / 135; int c = rem & 63; int b = rem >> 6;
    float y = 0.f;
#pragma unroll
    for (int q = 0; q < 8; ++q) y += pb[idx + (size_t)q * 552960];
    int hp = p / 15, wp = p % 15;
    float sc = 0.f;
    for (int ci = 0; ci < 32; ++ci) {
        size_t off = ((size_t)(b * 32 + ci) * 18 + hp * 2) * 30 + wp * 2;
        float hv = h2a[off] + h2b[off];
        sc = fmaf(bnrelu(hv, g1l[ci], b1l[ci]), wscl[ci * 64 + c], sc);
    }
    float v = y + sc;
    xp[((size_t)b * 135 + p) * 64 + c] = bnrelu(v, bng[c] * BN_S, bnb[c]);
}

// ---------------- MFMA bilinear-pooling GEMM ----------------
// A_q[p,o] = sum_{c in quarter q} xp[p,c] * S_c[p,o],
// S_c[p,o] = sum_{k<=c} xp[p,k] * W[idx(k,c), o]   (MFMA over k)
// Block: 256 thr (4 waves), 128 pixels; wave w -> rows 32w..32w+31
// (2 row-tiles); all 64 outs (4 col-tiles). NCH = chunks per c (1 for c<32).
template<int NCH>
__global__ __launch_bounds__(256) void f2m_k(
    const float* __restrict__ xp, const short* __restrict__ wf,
    const float* __restrict__ ctb, float* __restrict__ Abase, int qbase)
{
    __shared__ unsigned short xs[128 * 64];  // bf16, 16B-group XOR-swizzled by (pix&7)
    const int t = threadIdx.x;
    const int p0 = blockIdx.x * 128;
    const int q = qbase + blockIdx.y;
    float* A = Abase + (size_t)q * 552960;

    {   // stage xp rows -> bf16 LDS (swizzled)
        int pr = t >> 1, h = t & 1;
        int gp = p0 + pr;
        float v[32];
        if (gp < 8640) {
            const float4* src = (const float4*)(xp + (size_t)gp * 64 + h * 32);
#pragma unroll
            for (int i = 0; i < 8; ++i) {
                float4 x4 = src[i];
                v[i*4+0] = x4.x; v[i*4+1] = x4.y; v[i*4+2] = x4.z; v[i*4+3] = x4.w;
            }
        } else {
#pragma unroll
            for (int i = 0; i < 32; ++i) v[i] = 0.f;
        }
#pragma unroll
        for (int g = 0; g < 4; ++g) {
            unsigned w0 = f2bf(v[g*8+0]) | ((unsigned)f2bf(v[g*8+1]) << 16);
            unsigned w1 = f2bf(v[g*8+2]) | ((unsigned)f2bf(v[g*8+3]) << 16);
            unsigned w2 = f2bf(v[g*8+4]) | ((unsigned)f2bf(v[g*8+5]) << 16);
            unsigned w3 = f2bf(v[g*8+6]) | ((unsigned)f2bf(v[g*8+7]) << 16);
            int grp = h * 4 + g;
            int sg = grp ^ (pr & 7);
            *(uint4*)&xs[pr * 64 + sg * 8] = make_uint4(w0, w1, w2, w3);
        }
    }
    __syncthreads();

    const int w = t >> 6, lane = t & 63;
    const int prow = w * 32;
    const int lrow = lane & 15, lk = lane >> 4;

    // A-fragments: loaded once, reused for every c
    bf16x8 Af[2][NCH];
#pragma unroll
    for (int rt = 0; rt < 2; ++rt)
#pragma unroll
        for (int ch = 0; ch < NCH; ++ch) {
            int pix = prow + rt * 16 + lrow;
            int g = ch * 4 + lk;
            Af[rt][ch] = *(const bf16x8*)&xs[pix * 64 + ((g ^ (pix & 7)) * 8)];
        }

    f32x4 acc[2][4];
#pragma unroll
    for (int rt = 0; rt < 2; ++rt)
#pragma unroll
        for (int tt = 0; tt < 4; ++tt) acc[rt][tt] = f32x4{0.f, 0.f, 0.f, 0.f};

    const int c0 = q * 16;
#pragma unroll 1
    for (int ci = 0; ci < 16; ++ci) {
        const int c = c0 + ci;
        const int slotb = (NCH == 1) ? c : (2 * c - 32);
        f32x4 S[2][4];
#pragma unroll
        for (int rt = 0; rt < 2; ++rt)
#pragma unroll
            for (int tt = 0; tt < 4; ++tt) S[rt][tt] = f32x4{0.f, 0.f, 0.f, 0.f};

#pragma unroll
        for (int ch = 0; ch < NCH; ++ch) {
            const short* wb = wf + (size_t)(slotb + ch) * 2048 + lane * 8;
#pragma unroll
            for (int tt = 0; tt < 4; ++tt) {
                bf16x8 B = *(const bf16x8*)(wb + tt * 512);
                S[0][tt] = __builtin_amdgcn_mfma_f32_16x16x32_bf16(Af[0][ch], B, S[0][tt], 0, 0, 0);
                S[1][tt] = __builtin_amdgcn_mfma_f32_16x16x32_bf16(Af[1][ch], B, S[1][tt], 0, 0, 0);
            }
        }
        // acc += xp[:,c] (diag) * S_c   (C/D layout: col=lane&15, row=lk*4+j)
#pragma unroll
        for (int rt = 0; rt < 2; ++rt)
#pragma unroll
            for (int j = 0; j < 4; ++j) {
                int pix = prow + rt * 16 + lk * 4 + j;
                float sv = bf2f(xs[pix * 64 + (((c >> 3) ^ (pix & 7)) * 8) + (c & 7)]);
#pragma unroll
                for (int tt = 0; tt < 4; ++tt)
                    acc[rt][tt][j] += sv * S[rt][tt][j];
            }
    }

#pragma unroll
    for (int rt = 0; rt < 2; ++rt)
#pragma unroll
        for (int j = 0; j < 4; ++j) {
            int gpix = p0 + prow + rt * 16 + lk * 4 + j;
            if (gpix < 8640) {
#pragma unroll
                for (int tt = 0; tt < 4; ++tt) {
                    int o = tt * 16 + lrow;
                    float vv = acc[rt][tt][j];
                    if (q == 0) vv += ctb[o];
                    A[(size_t)gpix * 64 + o] = vv;
                }
            }
        }
}

// ---------------- gating (unchanged) ----------------
__global__ void f3a_k(const float* __restrict__ A, float* __restrict__ G)
{
    int b = blockIdx.x; int t = threadIdx.x;
    int o = t & 63; int grp = t >> 6;
    float s = 0.f;
    for (int p = grp; p < 135; p += 4) {
        size_t off = ((size_t)b * 135 + p) * 64 + o;
        s += A[off] + A[off + 552960] + A[off + 2 * 552960] + A[off + 3 * 552960];
    }
    __shared__ float red[4][64];
    red[grp][o] = s;
    __syncthreads();
    if (t < 64) G[b * 64 + t] = (red[0][t] + red[1][t] + red[2][t] + red[3][t]) * (1.0f / 135.0f);
}

__global__ void f3b_k(const float* __restrict__ xp, const float* __restrict__ A,
                      const float* __restrict__ G, float* __restrict__ out)
{
    int idx = blockIdx.x * 256 + threadIdx.x;
    if (idx >= BATCH * 135 * 64) return;
    int o = idx & 63; int b = idx / (135 * 64);
    float a = A[idx] + A[idx + 552960] + A[idx + 2 * 552960] + A[idx + 3 * 552960];
    float g = G[b * 64 + o];
    float x = xp[idx];
    out[idx] = fmaf(x, a * (g + 1.f), x);
}

extern "C" void kernel_launch(void* const* d_in, const int* in_sizes, int n_in,
                              void* d_out, int out_size, void* d_ws, size_t ws_size,
                              hipStream_t stream)
{
    const float* x      = (const float*)d_in[0];
    const float* conv_w = (const float*)d_in[2];
    const float* s1_g1  = (const float*)d_in[3];
    const float* s1_b1  = (const float*)d_in[4];
    const float* s1_w1  = (const float*)d_in[5];
    const float* s1_g2  = (const float*)d_in[6];
    const float* s1_b2  = (const float*)d_in[7];
    const float* s1_w2  = (const float*)d_in[8];
    const float* s2_g1  = (const float*)d_in[9];
    const float* s2_b1  = (const float*)d_in[10];
    const float* s2_w1  = (const float*)d_in[11];
    const float* s2_g2  = (const float*)d_in[12];
    const float* s2_b2  = (const float*)d_in[13];
    const float* s2_w2  = (const float*)d_in[14];
    const float* s2_ws  = (const float*)d_in[15];
    const float* s3_g1  = (const float*)d_in[16];
    const float* s3_b1  = (const float*)d_in[17];
    const float* s3_w1  = (const float*)d_in[18];
    const float* s3_g2  = (const float*)d_in[19];
    const float* s3_b2  = (const float*)d_in[20];
    const float* s3_w2  = (const float*)d_in[21];
    const float* s3_ws  = (const float*)d_in[22];
    const float* bn_g   = (const float*)d_in[23];
    const float* bn_b   = (const float*)d_in[24];
    const float* ct_w   = (const float*)d_in[25];
    const float* ct_b   = (const float*)d_in[26];
    float* out = (float*)d_out;

    float* ws = (float*)d_ws;
    float* h0      = ws + 0;
    float* p_b1c1  = ws + 2211840;
    float* h1      = ws + 6635520;
    float* p_b2c1  = ws + 2211840;
    float* p_b2c2  = ws + 8847360;
    float* p_b3c1  = ws + 2211840;
    float* p_b3c2  = ws + 4423680;
    float* xp      = ws + 0;
    float* A       = ws + 552960;     // 4 partials
    float* G       = ws + 11059200;
    short* wfrag   = (short*)(ws + 11063296);  // 196608 bf16

    dim3 blk(256);

    f0_k<<<768, blk, 0, stream>>>(ct_w, wfrag);

    convT_k<3, 3, 16, 16, 36, 60, 36, 60, 1, 18, 5, 1, false, 0, 1, 1>
        <<<dim3(2, 64, 1), blk, 0, stream>>>(
        x, 0, conv_w, nullptr, nullptr, nullptr, nullptr, nullptr, nullptr, h0, 0);
    convT_k<16, 8, 16, 8, 36, 60, 36, 60, 1, 9, 5, 1, true, 0, 1, 1>
        <<<dim3(4, 64, 2), blk, 0, stream>>>(
        h0, 0, s1_w1, s1_g1, s1_b1, nullptr, nullptr, nullptr, nullptr, p_b1c1, 2211840);
    convT_k<16, 16, 16, 8, 36, 60, 36, 60, 1, 9, 5, 2, true, 1, 16, 1>
        <<<dim3(4, 64, 1), blk, 0, stream>>>(
        p_b1c1, 2211840, s1_w2, s1_g2, s1_b2, h0, s1_g1, s1_b1, nullptr, h1, 0);
    convT_k<16, 8, 32, 8, 36, 60, 18, 30, 2, 9, 5, 1, true, 0, 1, 1>
        <<<dim3(2, 64, 2), blk, 0, stream>>>(
        h1, 0, s2_w1, s2_g1, s2_b1, nullptr, nullptr, nullptr, nullptr, p_b2c1, 1105920);
    convT_k<32, 16, 32, 8, 18, 30, 18, 30, 1, 9, 5, 2, true, 2, 16, 2>
        <<<dim3(2, 64, 2), blk, 0, stream>>>(
        p_b2c1, 1105920, s2_w2, s2_g2, s2_b2, h1, s2_g1, s2_b1, s2_ws, p_b2c2, 1105920);
    convT_k<32, 8, 64, 8, 18, 30, 9, 15, 2, 9, 5, 2, true, 0, 1, 1>
        <<<dim3(1, 64, 4), blk, 0, stream>>>(
        p_b2c2, 1105920, s3_w1, s3_g1, s3_b1, nullptr, nullptr, nullptr, nullptr, p_b3c1, 552960);
    convT_k<64, 8, 64, 8, 9, 15, 9, 15, 1, 9, 5, 4, true, 0, 1, 1>
        <<<dim3(1, 64, 8), blk, 0, stream>>>(
        p_b3c1, 552960, s3_w2, s3_g2, s3_b2, nullptr, nullptr, nullptr, nullptr, p_b3c2, 552960);
    red_k<<<2160, blk, 0, stream>>>(p_b3c2, p_b2c2, p_b2c2 + 1105920,
                                    s3_g1, s3_b1, s3_ws, bn_g, bn_b, xp);

    // MFMA pooling GEMM: quarters 0,1 (c<32, 1 chunk) and 2,3 (2 chunks)
    f2m_k<1><<<dim3(68, 2), blk, 0, stream>>>(xp, wfrag, ct_b, A, 0);
    f2m_k<2><<<dim3(68, 2), blk, 0, stream>>>(xp, wfrag, ct_b, A, 2);

    f3a_k<<<64, blk, 0, stream>>>(A, G);
    f3b_k<<<2160, blk, 0, stream>>>(xp, A, G, out);
}

// Round 6
// 202.746 us; speedup vs baseline: 2.4909x; 1.3342x over previous
//
#include <hip/hip_runtime.h>

#define BN_S 0.9999950000374997f

constexpr int BATCH = 64;

typedef __attribute__((ext_vector_type(8))) short bf16x8;
typedef __attribute__((ext_vector_type(4))) float f32x4;

__device__ __forceinline__ float bnrelu(float x, float gs, float bb) {
    return fmaxf(fmaf(x, gs, bb), 0.f);
}

__device__ __forceinline__ unsigned short f2bf(float f) {
    unsigned u = __builtin_bit_cast(unsigned, f);
    return (unsigned short)((u + 0x7FFFu + ((u >> 16) & 1u)) >> 16);
}
__device__ __forceinline__ float bf2f(unsigned short h) {
    unsigned u = ((unsigned)h) << 16;
    return __builtin_bit_cast(float, u);
}

// ---------------- generic fused conv3x3 ----------------
// acts staged (PARTS partials summed, bnrelu'd, zero-padded) in LDS;
// weights in LDS; thread tile P pixels x CO_PER channels; CIN z-split;
// shortcut (SC=1 identity / SC=2 1x1-conv) sums SCPARTS partials, zci==0 only.
template<int CIN, int CICH, int COUT, int CO_PER, int HIN, int WIN,
         int HOUT, int WOUT, int STRIDE, int ROWS, int P, int PARTS,
         bool PRE_BN, int SC, int CSC, int SSTR, int SCPARTS>
__global__ __launch_bounds__(256) void convT_k(
    const float* __restrict__ in, size_t in_pstride,
    const float* __restrict__ w,
    const float* __restrict__ g, const float* __restrict__ bb,
    const float* __restrict__ xin, size_t xin_pstride,
    const float* __restrict__ g1v, const float* __restrict__ b1v,
    const float* __restrict__ wsc,
    float* __restrict__ out, size_t out_pstride)
{
    constexpr int IR = (STRIDE == 1) ? ROWS + 2 : 2 * ROWS + 1;
    constexpr int TW = (STRIDE == 1) ? WIN + 2 : WIN + 1;
    constexpr int AW = (P - 1) * STRIDE + 3;
    constexpr int NCOG = COUT / CO_PER;
    constexpr int PGW = WOUT / P;
    constexpr int NG = ROWS * PGW;
    constexpr int NITEMS = NG * NCOG;

    __shared__ float xs[CICH * IR * TW];
    __shared__ float wlds[CICH * 9 * COUT];
    __shared__ float g1l[SC ? CSC : 1], b1l[SC ? CSC : 1];
    __shared__ float wscl[(SC == 2) ? CSC * COUT : 1];

    const int band = blockIdx.x, b = blockIdx.y, zci = blockIdx.z;
    const int ci0 = zci * CICH;
    const int r0 = band * ROWS;
    const int r0in = r0 * STRIDE - 1;
    const int tid = threadIdx.x;

    for (int i = tid; i < CICH * 9 * COUT; i += 256) {
        int co = i % COUT; int rem = i / COUT; int tap = rem % 9; int ci = rem / 9;
        wlds[i] = w[((size_t)co * CIN + ci0 + ci) * 9 + tap];
    }
    if constexpr (SC != 0) {
        if (tid < CSC) { g1l[tid] = g1v[tid] * BN_S; b1l[tid] = b1v[tid]; }
        if constexpr (SC == 2) {
            for (int i = tid; i < CSC * COUT; i += 256) {
                int co = i % COUT; int ci = i / COUT;
                wscl[i] = wsc[(size_t)co * CSC + ci];
            }
        }
    }
    for (int i = tid; i < CICH * IR * TW; i += 256) {
        int cc = i % TW; int rem = i / TW; int rr = rem % IR; int ci = rem / IR;
        int gr = r0in + rr; int gc = cc - 1;
        float v = 0.f;
        if (gr >= 0 && gr < HIN && gc >= 0 && gc < WIN) {
            size_t off = ((size_t)(b * CIN + ci0 + ci) * HIN + gr) * WIN + gc;
            v = in[off];
            if constexpr (PARTS >= 2) v += in[off + in_pstride];
            if constexpr (PARTS >= 3) v += in[off + 2 * in_pstride];
            if constexpr (PARTS >= 4) v += in[off + 3 * in_pstride];
            if constexpr (PRE_BN) v = bnrelu(v, g[ci0 + ci] * BN_S, bb[ci0 + ci]);
        }
        xs[i] = v;
    }
    __syncthreads();

    for (int it = tid; it < NITEMS; it += 256) {
        const int cog = it / NG; const int gi = it % NG;
        const int lr = gi / PGW; const int wc = (gi % PGW) * P;
        float acc[P][CO_PER];
#pragma unroll
        for (int j = 0; j < P; ++j)
#pragma unroll
            for (int co = 0; co < CO_PER; ++co) acc[j][co] = 0.f;

        for (int ci = 0; ci < CICH; ++ci) {
            const float* xb = xs + ((ci * IR) + lr * STRIDE) * TW + wc * STRIDE;
#pragma unroll
            for (int dh = 0; dh < 3; ++dh) {
                float aw[AW];
#pragma unroll
                for (int a = 0; a < AW; ++a) aw[a] = xb[dh * TW + a];
#pragma unroll
                for (int dw = 0; dw < 3; ++dw) {
                    const float* wp = wlds + (ci * 9 + dh * 3 + dw) * COUT + cog * CO_PER;
#pragma unroll
                    for (int c4 = 0; c4 < CO_PER; c4 += 4) {
                        float4 wv = *(const float4*)(wp + c4);
#pragma unroll
                        for (int j = 0; j < P; ++j) {
                            float a_ = aw[j * STRIDE + dw];
                            acc[j][c4 + 0] = fmaf(a_, wv.x, acc[j][c4 + 0]);
                            acc[j][c4 + 1] = fmaf(a_, wv.y, acc[j][c4 + 1]);
                            acc[j][c4 + 2] = fmaf(a_, wv.z, acc[j][c4 + 2]);
                            acc[j][c4 + 3] = fmaf(a_, wv.w, acc[j][c4 + 3]);
                        }
                    }
                }
            }
        }

        if constexpr (SC == 1) {
            if (zci == 0) {
#pragma unroll
                for (int co = 0; co < CO_PER; ++co) {
                    int c = cog * CO_PER + co;
#pragma unroll
                    for (int j = 0; j < P; ++j) {
                        size_t off = ((size_t)(b * CSC + c) * HOUT + (r0 + lr)) * WOUT + wc + j;
                        float v = xin[off];
#pragma unroll
                        for (int s = 1; s < SCPARTS; ++s) v += xin[off + s * xin_pstride];
                        acc[j][co] += bnrelu(v, g1l[c], b1l[c]);
                    }
                }
            }
        }
        if constexpr (SC == 2) {
            if (zci == 0) {
                const int hix = (r0 + lr) * SSTR;
                for (int ci = 0; ci < CSC; ++ci) {
                    float vv[P];
#pragma unroll
                    for (int j = 0; j < P; ++j) {
                        size_t off = ((size_t)(b * CSC + ci) * (HOUT * SSTR) + hix) * (WOUT * SSTR)
                                     + (wc + j) * SSTR;
                        float v = xin[off];
#pragma unroll
                        for (int s = 1; s < SCPARTS; ++s) v += xin[off + s * xin_pstride];
                        vv[j] = bnrelu(v, g1l[ci], b1l[ci]);
                    }
                    const float* wp = wscl + ci * COUT + cog * CO_PER;
#pragma unroll
                    for (int c4 = 0; c4 < CO_PER; c4 += 4) {
                        float4 wv = *(const float4*)(wp + c4);
#pragma unroll
                        for (int j = 0; j < P; ++j) {
                            acc[j][c4 + 0] = fmaf(vv[j], wv.x, acc[j][c4 + 0]);
                            acc[j][c4 + 1] = fmaf(vv[j], wv.y, acc[j][c4 + 1]);
                            acc[j][c4 + 2] = fmaf(vv[j], wv.z, acc[j][c4 + 2]);
                            acc[j][c4 + 3] = fmaf(vv[j], wv.w, acc[j][c4 + 3]);
                        }
                    }
                }
            }
        }

        float* op = out + (size_t)zci * out_pstride
                    + ((size_t)(b * COUT + cog * CO_PER) * HOUT + (r0 + lr)) * WOUT + wc;
#pragma unroll
        for (int co = 0; co < CO_PER; ++co)
#pragma unroll
            for (int j = 0; j < P; ++j)
                op[(size_t)co * HOUT * WOUT + j] = acc[j][co];
    }
}

// ---------------- Wfrag prep (bf16 MFMA B-fragments per column c) --------
__global__ void f0_k(const float* __restrict__ ctw, short* __restrict__ wf)
{
    int id = blockIdx.x * 256 + threadIdx.x;   // < 196608
    int j = id & 7; int lane = (id >> 3) & 63; int tile = (id >> 9) & 3; int s = id >> 11;
    int c, ch;
    if (s < 32) { c = s; ch = 0; }
    else { c = 32 + ((s - 32) >> 1); ch = (s - 32) & 1; }
    int k = ch * 32 + ((lane >> 4) << 3) + j;
    int o = tile * 16 + (lane & 15);
    float val = 0.f;
    if (k <= c) val = ctw[o * 2080 + (k * (129 - k)) / 2 + (c - k)];
    wf[id] = (short)f2bf(val);
}

// ---------------- reduce b3c2 -> xp ----------------
// grid (64, 4): b x c-quarter. Stage bnrelu1(sum4 h2) per (ci,p) in LDS once,
// then each element: sum 8 conv partials + LDS-based 1x1 shortcut + final bn.
__global__ __launch_bounds__(256) void red_k(
    const float* __restrict__ pb, const float* __restrict__ h2,
    const float* __restrict__ g1, const float* __restrict__ b1,
    const float* __restrict__ wsc, const float* __restrict__ bng,
    const float* __restrict__ bnb, float* __restrict__ xp)
{
    __shared__ float hsc[32][136];
    __shared__ float wscl[32][16];
    __shared__ float g1l[32], b1l[32];
    const int b = blockIdx.x, cq = blockIdx.y;
    const int c0 = cq * 16;
    const int t = threadIdx.x;

    if (t < 32) { g1l[t] = g1[t] * BN_S; b1l[t] = b1[t]; }
    for (int i = t; i < 512; i += 256) {
        int ci = i & 31, cc = i >> 5;
        wscl[ci][cc] = wsc[(size_t)(c0 + cc) * 32 + ci];
    }
    __syncthreads();
    for (int i = t; i < 32 * 135; i += 256) {
        int ci = i / 135, p = i % 135;
        int hp = p / 15, wp = p % 15;
        size_t off = ((size_t)(b * 32 + ci) * 18 + hp * 2) * 30 + wp * 2;
        float v = h2[off] + h2[off + 1105920] + h2[off + 2 * 1105920] + h2[off + 3 * 1105920];
        hsc[ci][p] = bnrelu(v, g1l[ci], b1l[ci]);
    }
    __syncthreads();

    for (int e = t; e < 16 * 135; e += 256) {
        int cc = e / 135, p = e % 135;
        int c = c0 + cc;
        size_t idx = ((size_t)(b * 64 + c)) * 135 + p;
        float y = 0.f;
#pragma unroll
        for (int q = 0; q < 8; ++q) y += pb[idx + (size_t)q * 552960];
#pragma unroll 8
        for (int ci = 0; ci < 32; ++ci) y = fmaf(hsc[ci][p], wscl[ci][cc], y);
        xp[((size_t)b * 135 + p) * 64 + c] = bnrelu(y, bng[c] * BN_S, bnb[c]);
    }
}

// ---------------- MFMA bilinear-pooling GEMM ----------------
template<int NCH>
__device__ __forceinline__ void f2m_body(
    const unsigned short* xs, int q, const short* __restrict__ wf,
    const float* __restrict__ ctb, float* __restrict__ Abase, int p0, int t)
{
    float* A = Abase + (size_t)q * 552960;
    const int w = t >> 6, lane = t & 63;
    const int prow = w * 32;
    const int lrow = lane & 15, lk = lane >> 4;

    bf16x8 Af[2][NCH];
#pragma unroll
    for (int rt = 0; rt < 2; ++rt)
#pragma unroll
        for (int ch = 0; ch < NCH; ++ch) {
            int pix = prow + rt * 16 + lrow;
            int g = ch * 4 + lk;
            Af[rt][ch] = *(const bf16x8*)&xs[pix * 64 + ((g ^ (pix & 7)) * 8)];
        }

    f32x4 acc[2][4];
#pragma unroll
    for (int rt = 0; rt < 2; ++rt)
#pragma unroll
        for (int tt = 0; tt < 4; ++tt) acc[rt][tt] = f32x4{0.f, 0.f, 0.f, 0.f};

    const int c0 = q * 16;
    bf16x8 BA[NCH][4], BB[NCH][4];

    auto loadB = [&](int c, bf16x8 (&B)[NCH][4]) {
        int slotb = (NCH == 1) ? c : (2 * c - 32);
#pragma unroll
        for (int ch = 0; ch < NCH; ++ch) {
            const short* wb = wf + (size_t)(slotb + ch) * 2048 + lane * 8;
#pragma unroll
            for (int tt = 0; tt < 4; ++tt)
                B[ch][tt] = *(const bf16x8*)(wb + tt * 512);
        }
    };
    auto compute = [&](int c, bf16x8 (&B)[NCH][4]) {
        f32x4 S[2][4];
#pragma unroll
        for (int rt = 0; rt < 2; ++rt)
#pragma unroll
            for (int tt = 0; tt < 4; ++tt) S[rt][tt] = f32x4{0.f, 0.f, 0.f, 0.f};
#pragma unroll
        for (int ch = 0; ch < NCH; ++ch)
#pragma unroll
            for (int tt = 0; tt < 4; ++tt) {
                S[0][tt] = __builtin_amdgcn_mfma_f32_16x16x32_bf16(Af[0][ch], B[ch][tt], S[0][tt], 0, 0, 0);
                S[1][tt] = __builtin_amdgcn_mfma_f32_16x16x32_bf16(Af[1][ch], B[ch][tt], S[1][tt], 0, 0, 0);
            }
#pragma unroll
        for (int rt = 0; rt < 2; ++rt)
#pragma unroll
            for (int j = 0; j < 4; ++j) {
                int pix = prow + rt * 16 + lk * 4 + j;
                float sv = bf2f(xs[pix * 64 + (((c >> 3) ^ (pix & 7)) * 8) + (c & 7)]);
#pragma unroll
                for (int tt = 0; tt < 4; ++tt)
                    acc[rt][tt][j] += sv * S[rt][tt][j];
            }
    };

    loadB(c0, BA);
#pragma unroll 1
    for (int ci = 0; ci < 16; ci += 2) {
        loadB(c0 + ci + 1, BB);
        compute(c0 + ci, BA);
        if (ci < 14) loadB(c0 + ci + 2, BA);
        compute(c0 + ci + 1, BB);
    }

#pragma unroll
    for (int rt = 0; rt < 2; ++rt)
#pragma unroll
        for (int j = 0; j < 4; ++j) {
            int gpix = p0 + prow + rt * 16 + lk * 4 + j;
            if (gpix < 8640) {
#pragma unroll
                for (int tt = 0; tt < 4; ++tt) {
                    int o = tt * 16 + lrow;
                    float vv = acc[rt][tt][j];
                    if (q == 0) vv += ctb[o];
                    A[(size_t)gpix * 64 + o] = vv;
                }
            }
        }
}

__global__ __launch_bounds__(256) void f2m_k(
    const float* __restrict__ xp, const short* __restrict__ wf,
    const float* __restrict__ ctb, float* __restrict__ Abase)
{
    __shared__ unsigned short xs[128 * 64];
    const int t = threadIdx.x;
    const int p0 = blockIdx.x * 128;
    const int q = blockIdx.y;

    {
        int pr = t >> 1, h = t & 1;
        int gp = p0 + pr;
        float v[32];
        if (gp < 8640) {
            const float4* src = (const float4*)(xp + (size_t)gp * 64 + h * 32);
#pragma unroll
            for (int i = 0; i < 8; ++i) {
                float4 x4 = src[i];
                v[i*4+0] = x4.x; v[i*4+1] = x4.y; v[i*4+2] = x4.z; v[i*4+3] = x4.w;
            }
        } else {
#pragma unroll
            for (int i = 0; i < 32; ++i) v[i] = 0.f;
        }
#pragma unroll
        for (int g = 0; g < 4; ++g) {
            unsigned w0 = f2bf(v[g*8+0]) | ((unsigned)f2bf(v[g*8+1]) << 16);
            unsigned w1 = f2bf(v[g*8+2]) | ((unsigned)f2bf(v[g*8+3]) << 16);
            unsigned w2 = f2bf(v[g*8+4]) | ((unsigned)f2bf(v[g*8+5]) << 16);
            unsigned w3 = f2bf(v[g*8+6]) | ((unsigned)f2bf(v[g*8+7]) << 16);
            int grp = h * 4 + g;
            int sg = grp ^ (pr & 7);
            *(uint4*)&xs[pr * 64 + sg * 8] = make_uint4(w0, w1, w2, w3);
        }
    }
    __syncthreads();

    if (q < 2) f2m_body<1>(xs, q, wf, ctb, Abase, p0, t);
    else       f2m_body<2>(xs, q, wf, ctb, Abase, p0, t);
}

// ---------------- gating ----------------
__global__ void f3a_k(const float* __restrict__ A, float* __restrict__ G)
{
    int b = blockIdx.x; int t = threadIdx.x;
    int o = t & 63; int grp = t >> 6;
    float s = 0.f;
    for (int p = grp; p < 135; p += 4) {
        size_t off = ((size_t)b * 135 + p) * 64 + o;
        s += A[off] + A[off + 552960] + A[off + 2 * 552960] + A[off + 3 * 552960];
    }
    __shared__ float red[4][64];
    red[grp][o] = s;
    __syncthreads();
    if (t < 64) G[b * 64 + t] = (red[0][t] + red[1][t] + red[2][t] + red[3][t]) * (1.0f / 135.0f);
}

__global__ void f3b_k(const float* __restrict__ xp, const float* __restrict__ A,
                      const float* __restrict__ G, float* __restrict__ out)
{
    int idx = blockIdx.x * 256 + threadIdx.x;
    if (idx >= BATCH * 135 * 64) return;
    int o = idx & 63; int b = idx / (135 * 64);
    float a = A[idx] + A[idx + 552960] + A[idx + 2 * 552960] + A[idx + 3 * 552960];
    float g = G[b * 64 + o];
    float x = xp[idx];
    out[idx] = fmaf(x, a * (g + 1.f), x);
}

extern "C" void kernel_launch(void* const* d_in, const int* in_sizes, int n_in,
                              void* d_out, int out_size, void* d_ws, size_t ws_size,
                              hipStream_t stream)
{
    const float* x      = (const float*)d_in[0];
    const float* conv_w = (const float*)d_in[2];
    const float* s1_g1  = (const float*)d_in[3];
    const float* s1_b1  = (const float*)d_in[4];
    const float* s1_w1  = (const float*)d_in[5];
    const float* s1_g2  = (const float*)d_in[6];
    const float* s1_b2  = (const float*)d_in[7];
    const float* s1_w2  = (const float*)d_in[8];
    const float* s2_g1  = (const float*)d_in[9];
    const float* s2_b1  = (const float*)d_in[10];
    const float* s2_w1  = (const float*)d_in[11];
    const float* s2_g2  = (const float*)d_in[12];
    const float* s2_b2  = (const float*)d_in[13];
    const float* s2_w2  = (const float*)d_in[14];
    const float* s2_ws  = (const float*)d_in[15];
    const float* s3_g1  = (const float*)d_in[16];
    const float* s3_b1  = (const float*)d_in[17];
    const float* s3_w1  = (const float*)d_in[18];
    const float* s3_g2  = (const float*)d_in[19];
    const float* s3_b2  = (const float*)d_in[20];
    const float* s3_w2  = (const float*)d_in[21];
    const float* s3_ws  = (const float*)d_in[22];
    const float* bn_g   = (const float*)d_in[23];
    const float* bn_b   = (const float*)d_in[24];
    const float* ct_w   = (const float*)d_in[25];
    const float* ct_b   = (const float*)d_in[26];
    float* out = (float*)d_out;

    float* ws = (float*)d_ws;
    // region plan (floats). Live-range audit (r5 bug was h1 partial-1
    // [13271040,15482880) overlapping wfrag; wfrag/G now ABOVE all conv
    // regions; total 15585536 floats = 59.5 MiB < ws_size (256 MiB fill
    // observed in profile)):
    float* h0      = ws + 0;          // [0, 2211840)        stem out, dies after b1c2
    float* p_b1c1  = ws + 2211840;    // 4x2211840 [2211840, 11059200), dies after b1c2
    float* h1      = ws + 11059200;   // 2x2211840 [11059200, 15482880), dies after b2c2
    float* p_b2c1  = ws + 0;          // 4x1105920 [0, 4423680)       (h0 dead)
    float* p_b2c2  = ws + 4423680;    // 4x1105920 [4423680, 8847360), dies after red
    float* p_b3c1  = ws + 0;          // 4x552960  [0, 2211840)       (p_b2c1 dead)
    float* p_b3c2  = ws + 8847360;    // 8x552960  [8847360, 13271040) (inside dead p_b1c1.. h1 p0 tail? no: h1 p0 = [11059200,13271040) dies only after b2c2; b3c2 runs after b2c2 -> ok)
    float* xp      = ws + 0;          // [0, 552960)                  (p_b3c1 dead)
    float* A       = ws + 552960;     // 4x552960  [552960, 2764800)
    float* G       = ws + 15482880;   // [15482880, 15487232)
    short* wfrag   = (short*)(ws + 15487232);  // 196608 bf16 [15487232, 15585536)

    dim3 blk(256);

    f0_k<<<768, blk, 0, stream>>>(ct_w, wfrag);

    // stem: 3->16, ROWS=6, P=3, CO_PER=8 -> grid 384
    convT_k<3, 3, 16, 8, 36, 60, 36, 60, 1, 6, 3, 1, false, 0, 1, 1, 1>
        <<<dim3(6, 64, 1), blk, 0, stream>>>(
        x, 0, conv_w, nullptr, nullptr, nullptr, 0, nullptr, nullptr, nullptr, h0, 0);
    // b1c1: 16->16, CICH=4 z=4, ROWS=9 -> grid 1024
    convT_k<16, 4, 16, 8, 36, 60, 36, 60, 1, 9, 5, 1, true, 0, 1, 1, 1>
        <<<dim3(4, 64, 4), blk, 0, stream>>>(
        h0, 0, s1_w1, s1_g1, s1_b1, nullptr, 0, nullptr, nullptr, nullptr, p_b1c1, 2211840);
    // b1c2: sum4 -> conv 16->16, CICH=8 z=2 + identity sc(h0) -> grid 512
    convT_k<16, 8, 16, 8, 36, 60, 36, 60, 1, 9, 5, 4, true, 1, 16, 1, 1>
        <<<dim3(4, 64, 2), blk, 0, stream>>>(
        p_b1c1, 2211840, s1_w2, s1_g2, s1_b2, h0, 0, s1_g1, s1_b1, nullptr, h1, 2211840);
    // b2c1: sum2 -> conv 16->32 stride2, CICH=4 z=4, ROWS=6 -> grid 768
    convT_k<16, 4, 32, 8, 36, 60, 18, 30, 2, 6, 5, 2, true, 0, 1, 1, 1>
        <<<dim3(3, 64, 4), blk, 0, stream>>>(
        h1, 2211840, s2_w1, s2_g1, s2_b1, nullptr, 0, nullptr, nullptr, nullptr, p_b2c1, 1105920);
    // b2c2: sum4 -> conv 32->32, CICH=8 z=4 + 1x1 sc(h1 sum2) -> grid 768
    convT_k<32, 8, 32, 8, 18, 30, 18, 30, 1, 6, 5, 4, true, 2, 16, 2, 2>
        <<<dim3(3, 64, 4), blk, 0, stream>>>(
        p_b2c1, 1105920, s2_w2, s2_g2, s2_b2, h1, 2211840, s2_g1, s2_b1, s2_ws, p_b2c2, 1105920);
    // b3c1: sum4 -> conv 32->64 stride2, CICH=8 z=4, ROWS=3, P=3, CO_PER=4 -> grid 768
    convT_k<32, 8, 64, 4, 18, 30, 9, 15, 2, 3, 3, 4, true, 0, 1, 1, 1>
        <<<dim3(3, 64, 4), blk, 0, stream>>>(
        p_b2c2, 1105920, s3_w1, s3_g1, s3_b1, nullptr, 0, nullptr, nullptr, nullptr, p_b3c1, 552960);
    // b3c2: sum4 -> conv 64->64, CICH=8 z=8 -> grid 1536 (shortcut in red)
    convT_k<64, 8, 64, 4, 9, 15, 9, 15, 1, 3, 3, 4, true, 0, 1, 1, 1>
        <<<dim3(3, 64, 8), blk, 0, stream>>>(
        p_b3c1, 552960, s3_w2, s3_g2, s3_b2, nullptr, 0, nullptr, nullptr, nullptr, p_b3c2, 552960);
    // reduce: 8 partials + 1x1 sc(bnrelu1(sum4 h2)) + final bn -> xp (NHWC)
    red_k<<<dim3(64, 4), blk, 0, stream>>>(p_b3c2, p_b2c2,
                                           s3_g1, s3_b1, s3_ws, bn_g, bn_b, xp);
    // MFMA pooling GEMM: 4 c-quarters in one launch
    f2m_k<<<dim3(68, 4), blk, 0, stream>>>(xp, wfrag, ct_b, A);

    f3a_k<<<64, blk, 0, stream>>>(A, G);
    f3b_k<<<2160, blk, 0, stream>>>(xp, A, G, out);
}